// Round 8
// baseline (94013.599 us; speedup 1.0000x reference)
//
#include <hip/hip_runtime.h>
#include <math.h>

#define BB 32
#define TENC 200
#define NMELS 80
#define TMELS 400
#define STEPS 200
#define MEM 256
#define PRE1N 256
#define PRE2N 128
#define AD 128
#define DK 21
#define DF 8
#define SK 21
#define SF 8
#define PL 11

// workspace offsets (floats)
#define WS_W640   0u
#define WS_W768   655360u
#define WS_ATTWT  1441792u
#define WS_ATTVT  1474560u
#define WS_PW1T   1496064u
#define WS_PW2T   1516544u
#define WS_PRE2   1549312u
#define WS_ALIGN  2368512u
#define WS_CTX2   2374912u
#define WS_H1     2391296u
#define WS_C1     2407680u
#define WS_H2     2415872u
#define WS_C2     2432256u
#define WS_FBUF   2440448u
#define WS_PBUF   2491648u
#define WS_BAR    2498048u
#define SLOT 8192u
#define G_NBLK 120
#define NGRP 15

// dynamic-LDS layouts (floats)
#define DYNF 38016
#define DYNB (DYNF*4)
// LSTM blocks: weights ch*4224 at 0; act buffer:
#define LACT 25344
// DCA blocks:
#define DQW 0
#define DTB 32768
#define DVV 32896
#define DWB 33024
#define DUU 33152
#define DTT 34176
#define DH1 35200
#define DQS 35456
#define DGS 35584
#define DRB 35760
#define DAL 35776
#define DPS 35976
#define DES 36176
#define DFS 36376
// proj blocks:
#define PW 0
#define PHC 8320
// conv blocks:
#define CF 0
#define CP 192
#define CA 256

__device__ __forceinline__ float sigm(float x){ return 1.f/(1.f+expf(-x)); }
__device__ __forceinline__ float tanh_fast(float x){
  float ax = fabsf(x);
  float z = __expf(-2.f*ax);
  float r = (1.f - z)/(1.f + z);
  return (x < 0.f) ? -r : r;
}
__device__ __forceinline__ float ld_cg(const float* p){
  return __hip_atomic_load(p, __ATOMIC_RELAXED, __HIP_MEMORY_SCOPE_AGENT);
}
__device__ __forceinline__ void st_cg(float* p, float v){
  __hip_atomic_store(p, v, __ATOMIC_RELAXED, __HIP_MEMORY_SCOPE_AGENT);
}

// relaxed monotone two-level grid barrier (15 groups x 8)
__device__ __forceinline__ void gridbar(unsigned* B, int blk, unsigned it){
  __syncthreads();
  if (threadIdx.x == 0){
    unsigned* gc  = B + (blk >> 3) * 32;
    unsigned* top = B + 512;
    unsigned* gen = B + 544;
    asm volatile("s_waitcnt vmcnt(0)" ::: "memory");
    unsigned a = __hip_atomic_fetch_add(gc, 1u, __ATOMIC_RELAXED, __HIP_MEMORY_SCOPE_AGENT);
    if (a == 8u*it + 7u){
      unsigned b2 = __hip_atomic_fetch_add(top, 1u, __ATOMIC_RELAXED, __HIP_MEMORY_SCOPE_AGENT);
      if (b2 == (unsigned)NGRP*it + (NGRP-1u)){
        __hip_atomic_fetch_add(gen, 1u, __ATOMIC_RELAXED, __HIP_MEMORY_SCOPE_AGENT);
      } else {
        while (__hip_atomic_load(gen, __ATOMIC_RELAXED, __HIP_MEMORY_SCOPE_AGENT) <= it)
          __builtin_amdgcn_s_sleep(16);
      }
    } else {
      while (__hip_atomic_load(gen, __ATOMIC_RELAXED, __HIP_MEMORY_SCOPE_AGENT) <= it)
        __builtin_amdgcn_s_sleep(16);
    }
  }
  __syncthreads();
}

__global__ __launch_bounds__(256) void trk(const float* __restrict__ s, float* __restrict__ d, int R, int C){
  int i = blockIdx.x*256 + threadIdx.x;
  if (i < R*C){ int r = i / C, c = i - r*C; d[c*R + r] = s[i]; }
}

__global__ __launch_bounds__(256) void initk(float* __restrict__ ws){
  int b = blockIdx.x, tid = threadIdx.x;
  for (int i=tid;i<TENC;i+=256) ws[WS_ALIGN + b*TENC + i] = (i==0)?1.f:0.f;
  ws[WS_CTX2 + b*256u + tid]=0.f; ws[WS_CTX2 + SLOT + b*256u + tid]=0.f;
  ws[WS_H1   + b*256u + tid]=0.f; ws[WS_H1   + SLOT + b*256u + tid]=0.f;
  ws[WS_H2   + b*256u + tid]=0.f; ws[WS_H2   + SLOT + b*256u + tid]=0.f;
  ws[WS_C1   + b*256u + tid]=0.f; ws[WS_C2   + b*256u + tid]=0.f;
  if (b == 0){ for (int i=tid;i<640;i+=256) ws[WS_BAR + i] = 0.f; }
}

__global__ __launch_bounds__(256) void prenetk(const float* __restrict__ mels,
    const float* __restrict__ b1, const float* __restrict__ b2, float* __restrict__ ws){
  int t = blockIdx.x, tid = threadIdx.x;
  __shared__ float xS[BB*NMELS];
  __shared__ float p1S[BB*PRE1N];
  const float* W1T = ws + WS_PW1T;
  const float* W2T = ws + WS_PW2T;
  for (int i=tid;i<BB*NMELS;i+=256){
    int r = i/NMELS, k = i - r*NMELS;
    xS[i] = (t==0)?0.f : mels[r*NMELS*TMELS + k*TMELS + (2*t-1)];
  }
  __syncthreads();
  {
    float acc[BB];
    #pragma unroll
    for (int r=0;r<BB;r++) acc[r]=0.f;
    for (int k=0;k<NMELS;k++){
      float w = W1T[k*PRE1N + tid];
      #pragma unroll
      for (int r=0;r<BB;r++) acc[r] += xS[r*NMELS+k]*w;
    }
    float bb = b1[tid];
    #pragma unroll
    for (int r=0;r<BB;r++) p1S[r*PRE1N+tid] = fmaxf(acc[r]+bb, 0.f);
  }
  __syncthreads();
  if (tid < PRE2N){
    float acc[BB];
    #pragma unroll
    for (int r=0;r<BB;r++) acc[r]=0.f;
    for (int k=0;k<PRE1N;k++){
      float w = W2T[k*PRE2N + tid];
      #pragma unroll
      for (int r=0;r<BB;r++) acc[r] += p1S[r*PRE1N+k]*w;
    }
    float bb = b2[tid];
    #pragma unroll
    for (int r=0;r<BB;r++) ws[WS_PRE2 + ((unsigned)t*BB + r)*PRE2N + tid] = fmaxf(acc[r]+bb, 0.f);
  }
}

// persistent kernel, weights resident in LDS.
// roles: 0-31 LSTM1 | 32-63 LSTM2(t-1) | 64-71 convs | 72-103 DCA | 104-113 proj(t-1) | 114-119 idle
__global__ __launch_bounds__(256) void persist(
    const float* __restrict__ albih, const float* __restrict__ albhh,
    const float* __restrict__ dlbih, const float* __restrict__ dlbhh,
    const float* __restrict__ prior, const float* __restrict__ attF,
    const float* __restrict__ attWb, const float* __restrict__ attU,
    const float* __restrict__ attT, const float* __restrict__ attTb,
    const float* __restrict__ attv, const float* __restrict__ memory,
    const float* __restrict__ acW, const float* __restrict__ acb,
    float* __restrict__ ws, float* __restrict__ out){
  extern __shared__ float sm[];
  const int blk = blockIdx.x, tid = threadIdx.x;
  unsigned* bar = (unsigned*)(ws + WS_BAR);
  unsigned bar_it = 0;

  // ---------- one-time LDS staging ----------
  if (blk < 32){
    const float* W = ws + WS_W640;
    for (int ch = 0; ch < 5; ch++)
      for (int idx = tid; idx < 4096; idx += 256){
        int c = idx & 31, kl = idx >> 5;
        int col = 256*(c>>3) + 8*blk + (c&7);
        sm[ch*4224 + c*132 + kl] = W[(unsigned)(ch*128+kl)*1024u + col];
      }
  } else if (blk < 64){
    const float* W = ws + WS_W768; const int j2 = blk-32;
    for (int ch = 0; ch < 6; ch++)
      for (int idx = tid; idx < 4096; idx += 256){
        int c = idx & 31, kl = idx >> 5;
        int col = 256*(c>>3) + 8*j2 + (c&7);
        sm[ch*4224 + c*132 + kl] = W[(unsigned)(ch*128+kl)*1024u + col];
      }
  } else if (blk < 72){
    if (tid < SF*SK) sm[CF+tid] = attF[tid];
    if (tid < PL)    sm[CP+tid] = prior[tid];
  } else if (blk < 104){
    for (int i = tid; i < 32768; i += 256) sm[DQW+i] = ws[WS_ATTWT + i];
    if (tid < AD){ sm[DTB+tid] = attTb[tid]; sm[DVV+tid] = attv[tid]; sm[DWB+tid] = attWb[tid]; }
    for (int i = tid; i < AD*SF; i += 256) sm[DUU+i] = attU[i];
    for (int i = tid; i < AD*DF; i += 256) sm[DTT+i] = attT[i];
  } else if (blk < 114){
    const int p = blk - 104;
    for (int idx = tid; idx < 8192; idx += 256){
      int cl = idx >> 9, k = idx & 511;
      sm[PW + cl*520 + k] = acW[(unsigned)(16*p+cl)*512u + k];
    }
  }
  __syncthreads();

  for (int t = 0; t <= STEPS; ++t){
    const int wp = t & 1, rp = wp ^ 1;
    // ================= PHASE A =================
    if (blk < 32){
      if (t < STEPS){
        float* actS = sm + LACT;
        const int n_loc = tid & 7, b = tid >> 3;
        const int nn = 8*blk + n_loc;
        float acc0 = albih[nn]      + albhh[nn];
        float acc1 = albih[256+nn]  + albhh[256+nn];
        float acc2 = albih[512+nn]  + albhh[512+nn];
        float acc3 = albih[768+nn]  + albhh[768+nn];
        for (int ch = 0; ch < 5; ch++){
          const int k0 = ch*128;
          const float* src; int bstr; bool unc;
          if (ch < 2)      { src = ws + WS_CTX2 + rp*SLOT + k0;        bstr = 256; unc = true; }
          else if (ch == 2){ src = ws + WS_PRE2 + (unsigned)t*4096u;   bstr = 128; unc = false; }
          else             { src = ws + WS_H1   + rp*SLOT + (k0-384);  bstr = 256; unc = true; }
          if (unc){
            for (int idx = tid; idx < 4096; idx += 256){
              int bb = idx >> 7, kl = idx & 127;
              actS[bb*132 + kl] = ld_cg(&src[bb*bstr + kl]);
            }
          } else {
            for (int idx = tid; idx < 4096; idx += 256){
              int bb = idx >> 7, kl = idx & 127;
              actS[bb*132 + kl] = src[bb*bstr + kl];
            }
          }
          __syncthreads();
          const float* aR = actS + b*132;
          const float* w0 = sm + ch*4224 + (0*8+n_loc)*132;
          const float* w1 = sm + ch*4224 + (1*8+n_loc)*132;
          const float* w2 = sm + ch*4224 + (2*8+n_loc)*132;
          const float* w3 = sm + ch*4224 + (3*8+n_loc)*132;
          for (int kl = 0; kl < 128; kl += 4){
            float4 a4 = *(const float4*)(aR + kl);
            float4 x0 = *(const float4*)(w0 + kl);
            float4 x1 = *(const float4*)(w1 + kl);
            float4 x2 = *(const float4*)(w2 + kl);
            float4 x3 = *(const float4*)(w3 + kl);
            acc0 += a4.x*x0.x + a4.y*x0.y + a4.z*x0.z + a4.w*x0.w;
            acc1 += a4.x*x1.x + a4.y*x1.y + a4.z*x1.z + a4.w*x1.w;
            acc2 += a4.x*x2.x + a4.y*x2.y + a4.z*x2.z + a4.w*x2.w;
            acc3 += a4.x*x3.x + a4.y*x3.y + a4.z*x3.z + a4.w*x3.w;
          }
          __syncthreads();
        }
        float c_old = ws[WS_C1 + b*256u + nn];
        float cn = sigm(acc1)*c_old + sigm(acc0)*tanhf(acc2);
        float hn = sigm(acc3)*tanhf(cn);
        ws[WS_C1 + b*256u + nn] = cn;
        st_cg(&ws[WS_H1 + wp*SLOT + b*256u + nn], hn);
      }
    } else if (blk < 64){
      if (t >= 1){
        float* actS = sm + LACT;
        const int j2 = blk - 32;
        const int n_loc = tid & 7, b = tid >> 3;
        const int nn = 8*j2 + n_loc;
        float acc0 = dlbih[nn]      + dlbhh[nn];
        float acc1 = dlbih[256+nn]  + dlbhh[256+nn];
        float acc2 = dlbih[512+nn]  + dlbhh[512+nn];
        float acc3 = dlbih[768+nn]  + dlbhh[768+nn];
        for (int ch = 0; ch < 6; ch++){
          const int k0 = ch*128;
          const float* src;
          if (ch < 2)      src = ws + WS_H1   + rp*SLOT + k0;
          else if (ch < 4) src = ws + WS_CTX2 + rp*SLOT + (k0-256);
          else             src = ws + WS_H2   + wp*SLOT + (k0-512);
          for (int idx = tid; idx < 4096; idx += 256){
            int bb = idx >> 7, kl = idx & 127;
            actS[bb*132 + kl] = ld_cg(&src[bb*256 + kl]);
          }
          __syncthreads();
          const float* aR = actS + b*132;
          const float* w0 = sm + ch*4224 + (0*8+n_loc)*132;
          const float* w1 = sm + ch*4224 + (1*8+n_loc)*132;
          const float* w2 = sm + ch*4224 + (2*8+n_loc)*132;
          const float* w3 = sm + ch*4224 + (3*8+n_loc)*132;
          for (int kl = 0; kl < 128; kl += 4){
            float4 a4 = *(const float4*)(aR + kl);
            float4 x0 = *(const float4*)(w0 + kl);
            float4 x1 = *(const float4*)(w1 + kl);
            float4 x2 = *(const float4*)(w2 + kl);
            float4 x3 = *(const float4*)(w3 + kl);
            acc0 += a4.x*x0.x + a4.y*x0.y + a4.z*x0.z + a4.w*x0.w;
            acc1 += a4.x*x1.x + a4.y*x1.y + a4.z*x1.z + a4.w*x1.w;
            acc2 += a4.x*x2.x + a4.y*x2.y + a4.z*x2.z + a4.w*x2.w;
            acc3 += a4.x*x3.x + a4.y*x3.y + a4.z*x3.z + a4.w*x3.w;
          }
          __syncthreads();
        }
        float c_old = ws[WS_C2 + b*256u + nn];
        float cn = sigm(acc1)*c_old + sigm(acc0)*tanhf(acc2);
        float hn = sigm(acc3)*tanhf(cn);
        ws[WS_C2 + b*256u + nn] = cn;
        st_cg(&ws[WS_H2 + rp*SLOT + b*256u + nn], hn);
      }
    } else if (blk < 72){
      if (t < STEPS){
        const int j3 = blk - 64;
        const int bg = tid >> 6, lane = tid & 63;
        const int b = j3*4 + bg;
        float* alS4 = sm + CA;
        for (int pos = lane; pos < TENC; pos += 64) alS4[bg*TENC+pos] = ld_cg(&ws[WS_ALIGN + b*TENC + pos]);
        __syncthreads();
        for (int pos = lane; pos < TENC; pos += 64){
          float s = 0.f;
          #pragma unroll
          for (int jj = 0; jj < PL; jj++){ int q = pos - jj; if (q >= 0) s += sm[CP+jj]*alS4[bg*TENC+q]; }
          st_cg(&ws[WS_PBUF + b*TENC + pos], logf(fmaxf(s, 1e-6f)));
        }
        for (int it = lane; it < SF*TENC; it += 64){
          int chn = it / TENC, pos = it - chn*TENC;
          float s = 0.f;
          #pragma unroll
          for (int k = 0; k < SK; k++){ int q = pos + k - 10; if (q>=0 && q<TENC) s += sm[CF+chn*SK+k]*alS4[bg*TENC+q]; }
          st_cg(&ws[WS_FBUF + b*SF*TENC + it], s);
        }
        __syncthreads();
      }
    }
    gridbar(bar, blk, bar_it++);
    // ================= PHASE B =================
    if (blk >= 72 && blk < 104){
      if (t < STEPS){
        const int b = blk - 72;
        sm[DH1+tid] = ld_cg(&ws[WS_H1 + wp*SLOT + b*256u + tid]);
        if (tid < TENC){ sm[DAL+tid] = ld_cg(&ws[WS_ALIGN + b*TENC + tid]); sm[DPS+tid] = ld_cg(&ws[WS_PBUF + b*TENC + tid]); }
        for (int i = tid; i < SF*TENC; i += 256) sm[DFS+i] = ld_cg(&ws[WS_FBUF + b*SF*TENC + i]);
        __syncthreads();
        if (tid < AD){
          float a = sm[DWB+tid];
          for (int k = 0; k < 256; k++) a += sm[DH1+k]*sm[DQW + k*AD + tid];
          sm[DQS+tid] = tanhf(a);
        }
        __syncthreads();
        if (tid < DF*DK){
          const float* attVT = ws + WS_ATTVT;
          float a = 0.f;
          for (int k = 0; k < AD; k++) a += sm[DQS+k]*attVT[k*(DF*DK) + tid];
          sm[DGS+tid] = a;
        }
        __syncthreads();
        if (tid < TENC){
          const int pos = tid;
          float g[DF];
          #pragma unroll
          for (int c = 0; c < DF; c++){
            float s = 0.f;
            #pragma unroll
            for (int k = 0; k < DK; k++){
              int q2 = pos + k - 10;
              if (q2 >= 0 && q2 < TENC) s += sm[DAL+q2]*sm[DGS + c*DK + k];
            }
            g[c] = s;
          }
          float pp = 0.f;
          for (int h = 0; h < AD; h++){
            float u = sm[DTB+h];
            #pragma unroll
            for (int s2 = 0; s2 < SF; s2++) u += sm[DUU + h*SF + s2]*sm[DFS + s2*TENC + pos];
            #pragma unroll
            for (int c = 0; c < DF; c++) u += sm[DTT + h*DF + c]*g[c];
            pp += sm[DVV+h]*tanh_fast(u);
          }
          sm[DES+pos] = pp + sm[DPS+pos];
        }
        __syncthreads();
        float ex;
        {
          float v = (tid < TENC) ? sm[DES+tid] : -3.0e38f;
          for (int o = 1; o < 64; o <<= 1) v = fmaxf(v, __shfl_xor(v, o));
          if ((tid & 63) == 0) sm[DRB + (tid>>6)] = v;
          __syncthreads();
          if (tid == 0){ sm[DRB+4] = fmaxf(fmaxf(sm[DRB],sm[DRB+1]), fmaxf(sm[DRB+2],sm[DRB+3])); }
          __syncthreads();
          float m = sm[DRB+4];
          ex = (tid < TENC) ? expf(sm[DES+tid]-m) : 0.f;
          float sv = ex;
          for (int o = 1; o < 64; o <<= 1) sv += __shfl_xor(sv, o);
          __syncthreads();
          if ((tid & 63) == 0) sm[DRB + (tid>>6)] = sv;
          __syncthreads();
          if (tid == 0){ sm[DRB+5] = 1.f/(sm[DRB]+sm[DRB+1]+sm[DRB+2]+sm[DRB+3]); }
          __syncthreads();
          float inv = sm[DRB+5];
          if (tid < TENC){
            float a = ex*inv;
            sm[DAL+tid] = a;
            st_cg(&ws[WS_ALIGN + b*TENC + tid], a);
            out[1024000 + b*TENC*STEPS + tid*STEPS + t] = a;
          }
        }
        __syncthreads();
        {
          float a0=0.f,a1=0.f,a2=0.f,a3=0.f;
          const float* mb = memory + (unsigned)b*TENC*MEM + tid;
          for (int p = 0; p < TENC; p += 4){
            a0 += sm[DAL+p  ]*mb[(p  )*MEM];
            a1 += sm[DAL+p+1]*mb[(p+1)*MEM];
            a2 += sm[DAL+p+2]*mb[(p+2)*MEM];
            a3 += sm[DAL+p+3]*mb[(p+3)*MEM];
          }
          st_cg(&ws[WS_CTX2 + wp*SLOT + b*256u + tid], (a0+a1)+(a2+a3));
        }
        __syncthreads();
      }
    } else if (blk >= 104 && blk < 114){
      if (t >= 1){
        const int p = blk - 104;
        for (int idx = tid; idx < 8192; idx += 256){
          int bb = idx >> 8, k = idx & 255;
          sm[PHC + bb*516 + k]       = ld_cg(&ws[WS_H2   + rp*SLOT + bb*256u + k]);
          sm[PHC + bb*516 + 256 + k] = ld_cg(&ws[WS_CTX2 + rp*SLOT + bb*256u + k]);
        }
        __syncthreads();
        #pragma unroll
        for (int oo = 0; oo < 2; oo++){
          const int o = tid + oo*256;
          const int b = o >> 4, cl = o & 15;
          const int col = 16*p + cl;
          float acc = acb[col];
          const float* hc = sm + PHC + b*516;
          const float* wv = sm + PW + cl*520;
          for (int k = 0; k < 512; k += 4){
            float4 h4 = *(const float4*)(hc + k);
            float4 w4 = *(const float4*)(wv + k);
            acc += h4.x*w4.x + h4.y*w4.y + h4.z*w4.z + h4.w*w4.w;
          }
          out[(unsigned)b*NMELS*TMELS + (col>>1)*TMELS + 2*(t-1) + (col&1)] = acc;
        }
        __syncthreads();
      }
    }
    gridbar(bar, blk, bar_it++);
  }
}

extern "C" void kernel_launch(void* const* d_in, const int* in_sizes, int n_in,
                              void* d_out, int out_size, void* d_ws, size_t ws_size,
                              hipStream_t stream) {
  (void)in_sizes; (void)n_in; (void)out_size; (void)ws_size;
  const float* mels   = (const float*)d_in[0];
  const float* memory = (const float*)d_in[1];
  const float* pre_W1 = (const float*)d_in[2];
  const float* pre_b1 = (const float*)d_in[3];
  const float* pre_W2 = (const float*)d_in[4];
  const float* pre_b2 = (const float*)d_in[5];
  const float* al_Wih = (const float*)d_in[6];
  const float* al_Whh = (const float*)d_in[7];
  const float* al_bih = (const float*)d_in[8];
  const float* al_bhh = (const float*)d_in[9];
  const float* att_W  = (const float*)d_in[10];
  const float* att_Wb = (const float*)d_in[11];
  const float* att_V  = (const float*)d_in[12];
  const float* att_F  = (const float*)d_in[13];
  const float* att_U  = (const float*)d_in[14];
  const float* att_T  = (const float*)d_in[15];
  const float* att_Tb = (const float*)d_in[16];
  const float* att_v  = (const float*)d_in[17];
  const float* prior  = (const float*)d_in[18];
  const float* dl_Wih = (const float*)d_in[19];
  const float* dl_Whh = (const float*)d_in[20];
  const float* dl_bih = (const float*)d_in[21];
  const float* dl_bhh = (const float*)d_in[22];
  const float* ac_W   = (const float*)d_in[23];
  const float* ac_b   = (const float*)d_in[24];
  float* ws  = (float*)d_ws;
  float* out = (float*)d_out;

  hipFuncSetAttribute((const void*)persist, hipFuncAttributeMaxDynamicSharedMemorySize, DYNB);

  auto TR = [&](const float* src, unsigned off, int R, int C){
    int n = R*C;
    trk<<<dim3((n+255)/256), dim3(256), 0, stream>>>(src, ws + off, R, C);
  };
  TR(al_Wih, WS_W640,              1024, 384);
  TR(al_Whh, WS_W640 + 384u*1024u, 1024, 256);
  TR(dl_Wih, WS_W768,              1024, 512);
  TR(dl_Whh, WS_W768 + 512u*1024u, 1024, 256);
  TR(att_W,  WS_ATTWT, 128, 256);
  TR(att_V,  WS_ATTVT, 168, 128);
  TR(pre_W1, WS_PW1T,  256, 80);
  TR(pre_W2, WS_PW2T,  128, 256);

  initk<<<dim3(BB), dim3(256), 0, stream>>>(ws);
  prenetk<<<dim3(STEPS), dim3(256), 0, stream>>>(mels, pre_b1, pre_b2, ws);

  persist<<<dim3(G_NBLK), dim3(256), DYNB, stream>>>(
      al_bih, al_bhh, dl_bih, dl_bhh, prior, att_F,
      att_Wb, att_U, att_T, att_Tb, att_v, memory,
      ac_W, ac_b, ws, out);
}

// Round 11
// 80555.206 us; speedup vs baseline: 1.1671x; 1.1671x over previous
//
#include <hip/hip_runtime.h>
#include <math.h>

#define BB 32
#define TENC 200
#define NMELS 80
#define TMELS 400
#define STEPS 200
#define MEM 256
#define PRE1N 256
#define PRE2N 128
#define AD 128
#define DK 21
#define DF 8
#define SK 21
#define SF 8
#define PL 11

// workspace offsets (floats)
#define WS_W640   0u
#define WS_W768   655360u
#define WS_ATTWT  1441792u
#define WS_ATTVT  1474560u
#define WS_PW1T   1496064u
#define WS_PW2T   1516544u
#define WS_PRE2   1549312u
#define WS_ALIGN  2368512u
#define WS_CTX2   2374912u
#define WS_H1     2391296u
#define WS_C1     2407680u
#define WS_H2     2415872u
#define WS_C2     2432256u
#define WS_BAR    2498048u
#define SLOT 8192u
#define G_NBLK 112
#define NGRP 14

// dynamic LDS (floats)
#define DYNF 38016
#define DYNB (DYNF*4)
// DCA layout
#define DQW 0
#define DUU 32768
#define DTT 33792
#define DTB 34816
#define DVV 34944
#define DWB 35072
#define DFF 35200
#define DPR 35368
#define DH1 35392
#define DQS 35648
#define DGS 35776
#define DRB 35952
#define DAL 35960
#define DES 36160
#define DFS 36360
// proj layout
#define PW 0
#define PHC 8320

typedef float f4v __attribute__((ext_vector_type(4)));

__device__ __forceinline__ float sigm(float x){ return 1.f/(1.f+expf(-x)); }
__device__ __forceinline__ float tanh_fast(float x){
  float ax = fabsf(x);
  float z = __expf(-2.f*ax);
  float r = (1.f - z)/(1.f + z);
  return (x < 0.f) ? -r : r;
}

// 64B uncached (coherent-point) load: 4 consecutive dwordx4, one address op.
// NOTE gfx950 asm syntax: offset:N must precede sc0 sc1.
__device__ __forceinline__ void ldg64B(f4v r[4], const f4v* p){
  asm volatile(
    "global_load_dwordx4 %0, %4, off sc0 sc1\n\t"
    "global_load_dwordx4 %1, %4, off offset:16 sc0 sc1\n\t"
    "global_load_dwordx4 %2, %4, off offset:32 sc0 sc1\n\t"
    "global_load_dwordx4 %3, %4, off offset:48 sc0 sc1\n\t"
    "s_waitcnt vmcnt(0)"
    : "=v"(r[0]), "=v"(r[1]), "=v"(r[2]), "=v"(r[3])
    : "v"(p) : "memory");
}
__device__ __forceinline__ f4v ldg16B(const f4v* p){
  f4v r;
  asm volatile("global_load_dwordx4 %0, %1, off sc0 sc1\n\ts_waitcnt vmcnt(0)"
               : "=v"(r) : "v"(p) : "memory");
  return r;
}
__device__ __forceinline__ void stg4B(float* p, float v){
  asm volatile("global_store_dword %0, %1, off sc0 sc1" :: "v"(p), "v"(v) : "memory");
}

// relaxed monotone two-level grid barrier (14 groups x 8) with backoff
__device__ __forceinline__ void gridbar(unsigned* B, int blk, unsigned it){
  __syncthreads();
  if (threadIdx.x == 0){
    unsigned* gc  = B + (blk >> 3) * 32;
    unsigned* top = B + 512;
    unsigned* gen = B + 544;
    asm volatile("s_waitcnt vmcnt(0)" ::: "memory");
    unsigned a = __hip_atomic_fetch_add(gc, 1u, __ATOMIC_RELAXED, __HIP_MEMORY_SCOPE_AGENT);
    bool done = false;
    if (a == 8u*it + 7u){
      unsigned b2 = __hip_atomic_fetch_add(top, 1u, __ATOMIC_RELAXED, __HIP_MEMORY_SCOPE_AGENT);
      if (b2 == (unsigned)NGRP*it + (NGRP-1u)){
        __hip_atomic_fetch_add(gen, 1u, __ATOMIC_RELAXED, __HIP_MEMORY_SCOPE_AGENT);
        done = true;
      }
    }
    if (!done){
      int spins = 0;
      while (__hip_atomic_load(gen, __ATOMIC_RELAXED, __HIP_MEMORY_SCOPE_AGENT) <= it){
        if (spins < 4)       __builtin_amdgcn_s_sleep(2);
        else if (spins < 12) __builtin_amdgcn_s_sleep(16);
        else                 __builtin_amdgcn_s_sleep(64);
        spins++;
      }
    }
  }
  __syncthreads();
}

__global__ __launch_bounds__(256) void trk(const float* __restrict__ s, float* __restrict__ d, int R, int C){
  int i = blockIdx.x*256 + threadIdx.x;
  if (i < R*C){ int r = i / C, c = i - r*C; d[c*R + r] = s[i]; }
}

__global__ __launch_bounds__(256) void initk(float* __restrict__ ws){
  int b = blockIdx.x, tid = threadIdx.x;
  ws[WS_CTX2 + b*256u + tid]=0.f; ws[WS_CTX2 + SLOT + b*256u + tid]=0.f;
  ws[WS_H1   + b*256u + tid]=0.f; ws[WS_H1   + SLOT + b*256u + tid]=0.f;
  ws[WS_H2   + b*256u + tid]=0.f; ws[WS_H2   + SLOT + b*256u + tid]=0.f;
  ws[WS_C1   + b*256u + tid]=0.f; ws[WS_C2   + b*256u + tid]=0.f;
  if (b == 0){ for (int i=tid;i<640;i+=256) ws[WS_BAR + i] = 0.f; }
}

__global__ __launch_bounds__(256) void prenetk(const float* __restrict__ mels,
    const float* __restrict__ b1, const float* __restrict__ b2, float* __restrict__ ws){
  int t = blockIdx.x, tid = threadIdx.x;
  __shared__ float xS[BB*NMELS];
  __shared__ float p1S[BB*PRE1N];
  const float* W1T = ws + WS_PW1T;
  const float* W2T = ws + WS_PW2T;
  for (int i=tid;i<BB*NMELS;i+=256){
    int r = i/NMELS, k = i - r*NMELS;
    xS[i] = (t==0)?0.f : mels[r*NMELS*TMELS + k*TMELS + (2*t-1)];
  }
  __syncthreads();
  {
    float acc[BB];
    #pragma unroll
    for (int r=0;r<BB;r++) acc[r]=0.f;
    for (int k=0;k<NMELS;k++){
      float w = W1T[k*PRE1N + tid];
      #pragma unroll
      for (int r=0;r<BB;r++) acc[r] += xS[r*NMELS+k]*w;
    }
    float bb = b1[tid];
    #pragma unroll
    for (int r=0;r<BB;r++) p1S[r*PRE1N+tid] = fmaxf(acc[r]+bb, 0.f);
  }
  __syncthreads();
  if (tid < PRE2N){
    float acc[BB];
    #pragma unroll
    for (int r=0;r<BB;r++) acc[r]=0.f;
    for (int k=0;k<PRE1N;k++){
      float w = W2T[k*PRE2N + tid];
      #pragma unroll
      for (int r=0;r<BB;r++) acc[r] += p1S[r*PRE1N+k]*w;
    }
    float bb = b2[tid];
    #pragma unroll
    for (int r=0;r<BB;r++) ws[WS_PRE2 + ((unsigned)t*BB + r)*PRE2N + tid] = fmaxf(acc[r]+bb, 0.f);
  }
}

// roles: 0-31 LSTM1 | 32-63 LSTM2(t-1) | 64-95 DCA (convs fused) | 96-105 proj(t-1) | 106-111 idle
__global__ __launch_bounds__(256) void persist(
    const float* __restrict__ albih, const float* __restrict__ albhh,
    const float* __restrict__ dlbih, const float* __restrict__ dlbhh,
    const float* __restrict__ prior, const float* __restrict__ attF,
    const float* __restrict__ attWb, const float* __restrict__ attU,
    const float* __restrict__ attT, const float* __restrict__ attTb,
    const float* __restrict__ attv, const float* __restrict__ memory,
    const float* __restrict__ acW, const float* __restrict__ acb,
    float* __restrict__ ws, float* __restrict__ out){
  extern __shared__ float sm[];
  const int blk = blockIdx.x, tid = threadIdx.x;
  unsigned* bar = (unsigned*)(ws + WS_BAR);
  unsigned bar_it = 0;

  // ---------- one-time LDS staging ----------
  if (blk < 32){
    const float* W = ws + WS_W640;
    for (int ch = 0; ch < 5; ch++)
      for (int idx = tid; idx < 4096; idx += 256){
        int c = idx & 31, kl = idx >> 5;
        int col = 256*(c>>3) + 8*blk + (c&7);
        sm[ch*4224 + c*132 + kl] = W[(unsigned)(ch*128+kl)*1024u + col];
      }
  } else if (blk < 64){
    const float* W = ws + WS_W768; const int j2 = blk-32;
    for (int ch = 0; ch < 6; ch++)
      for (int idx = tid; idx < 4096; idx += 256){
        int c = idx & 31, kl = idx >> 5;
        int col = 256*(c>>3) + 8*j2 + (c&7);
        sm[ch*4224 + c*132 + kl] = W[(unsigned)(ch*128+kl)*1024u + col];
      }
  } else if (blk < 96){
    for (int i = tid; i < 32768; i += 256) sm[DQW+i] = ws[WS_ATTWT + i];
    for (int i = tid; i < AD*SF; i += 256) sm[DUU+i] = attU[i];
    for (int i = tid; i < AD*DF; i += 256) sm[DTT+i] = attT[i];
    if (tid < AD){ sm[DTB+tid] = attTb[tid]; sm[DVV+tid] = attv[tid]; sm[DWB+tid] = attWb[tid]; }
    if (tid < SF*SK) sm[DFF+tid] = attF[tid];
    if (tid < PL)    sm[DPR+tid] = prior[tid];
    if (tid < TENC)  sm[DAL+tid] = (tid==0)?1.f:0.f;
  } else if (blk < 106){
    const int p = blk - 96;
    for (int idx = tid; idx < 8192; idx += 256){
      int cl = idx >> 9, k = idx & 511;
      sm[PW + cl*520 + k] = acW[(unsigned)(16*p+cl)*512u + k];
    }
  }
  __syncthreads();

  for (int t = 0; t <= STEPS; ++t){
    const int wp = t & 1, rp = wp ^ 1;
    // ================= PHASE A =================
    if (blk < 32){
      if (t < STEPS){
        float* actS = sm + 21120;
        const int n_loc = tid & 7, b = tid >> 3;
        const int nn = 8*blk + n_loc;
        const int kl0 = (tid & 7)*16;
        float acc0 = albih[nn]      + albhh[nn];
        float acc1 = albih[256+nn]  + albhh[256+nn];
        float acc2 = albih[512+nn]  + albhh[512+nn];
        float acc3 = albih[768+nn]  + albhh[768+nn];
        for (int ch = 0; ch < 5; ch++){
          f4v* d = (f4v*)(actS + b*132 + kl0);
          if (ch == 2){
            const f4v* s = (const f4v*)(ws + WS_PRE2 + (unsigned)t*4096u + b*128u + kl0);
            d[0]=s[0]; d[1]=s[1]; d[2]=s[2]; d[3]=s[3];
          } else {
            const float* base = (ch < 2) ? (ws + WS_CTX2 + rp*SLOT) : (ws + WS_H1 + rp*SLOT);
            const int koff = (ch==1 || ch==4) ? 128 : 0;
            f4v r[4];
            ldg64B(r, (const f4v*)(base + b*256u + koff + kl0));
            d[0]=r[0]; d[1]=r[1]; d[2]=r[2]; d[3]=r[3];
          }
          __syncthreads();
          const float* aR = actS + b*132;
          const float* w0 = sm + ch*4224 + (0*8+n_loc)*132;
          const float* w1 = sm + ch*4224 + (1*8+n_loc)*132;
          const float* w2 = sm + ch*4224 + (2*8+n_loc)*132;
          const float* w3 = sm + ch*4224 + (3*8+n_loc)*132;
          for (int kl = 0; kl < 128; kl += 4){
            float4 a4 = *(const float4*)(aR + kl);
            float4 x0 = *(const float4*)(w0 + kl);
            float4 x1 = *(const float4*)(w1 + kl);
            float4 x2 = *(const float4*)(w2 + kl);
            float4 x3 = *(const float4*)(w3 + kl);
            acc0 += a4.x*x0.x + a4.y*x0.y + a4.z*x0.z + a4.w*x0.w;
            acc1 += a4.x*x1.x + a4.y*x1.y + a4.z*x1.z + a4.w*x1.w;
            acc2 += a4.x*x2.x + a4.y*x2.y + a4.z*x2.z + a4.w*x2.w;
            acc3 += a4.x*x3.x + a4.y*x3.y + a4.z*x3.z + a4.w*x3.w;
          }
          __syncthreads();
        }
        float c_old = ws[WS_C1 + b*256u + nn];
        float cn = sigm(acc1)*c_old + sigm(acc0)*tanhf(acc2);
        float hn = sigm(acc3)*tanhf(cn);
        ws[WS_C1 + b*256u + nn] = cn;
        stg4B(&ws[WS_H1 + wp*SLOT + b*256u + nn], hn);
      }
    } else if (blk < 64){
      if (t >= 1){
        float* actS = sm + 25344;
        const int j2 = blk - 32;
        const int n_loc = tid & 7, b = tid >> 3;
        const int nn = 8*j2 + n_loc;
        const int kl0 = (tid & 7)*16;
        float acc0 = dlbih[nn]      + dlbhh[nn];
        float acc1 = dlbih[256+nn]  + dlbhh[256+nn];
        float acc2 = dlbih[512+nn]  + dlbhh[512+nn];
        float acc3 = dlbih[768+nn]  + dlbhh[768+nn];
        for (int ch = 0; ch < 6; ch++){
          const float* base;
          if (ch < 2)      base = ws + WS_H1   + rp*SLOT;
          else if (ch < 4) base = ws + WS_CTX2 + rp*SLOT;
          else             base = ws + WS_H2   + wp*SLOT;
          const int koff = (ch & 1) ? 128 : 0;
          f4v r[4];
          ldg64B(r, (const f4v*)(base + b*256u + koff + kl0));
          f4v* d = (f4v*)(actS + b*132 + kl0);
          d[0]=r[0]; d[1]=r[1]; d[2]=r[2]; d[3]=r[3];
          __syncthreads();
          const float* aR = actS + b*132;
          const float* w0 = sm + ch*4224 + (0*8+n_loc)*132;
          const float* w1 = sm + ch*4224 + (1*8+n_loc)*132;
          const float* w2 = sm + ch*4224 + (2*8+n_loc)*132;
          const float* w3 = sm + ch*4224 + (3*8+n_loc)*132;
          for (int kl = 0; kl < 128; kl += 4){
            float4 a4 = *(const float4*)(aR + kl);
            float4 x0 = *(const float4*)(w0 + kl);
            float4 x1 = *(const float4*)(w1 + kl);
            float4 x2 = *(const float4*)(w2 + kl);
            float4 x3 = *(const float4*)(w3 + kl);
            acc0 += a4.x*x0.x + a4.y*x0.y + a4.z*x0.z + a4.w*x0.w;
            acc1 += a4.x*x1.x + a4.y*x1.y + a4.z*x1.z + a4.w*x1.w;
            acc2 += a4.x*x2.x + a4.y*x2.y + a4.z*x2.z + a4.w*x2.w;
            acc3 += a4.x*x3.x + a4.y*x3.y + a4.z*x3.z + a4.w*x3.w;
          }
          __syncthreads();
        }
        float c_old = ws[WS_C2 + b*256u + nn];
        float cn = sigm(acc1)*c_old + sigm(acc0)*tanhf(acc2);
        float hn = sigm(acc3)*tanhf(cn);
        ws[WS_C2 + b*256u + nn] = cn;
        stg4B(&ws[WS_H2 + rp*SLOT + b*256u + nn], hn);
      }
    }
    gridbar(bar, blk, bar_it++);
    // ================= PHASE B =================
    if (blk >= 64 && blk < 96){
      if (t < STEPS){
        const int b = blk - 64;
        if (tid < 64) ((f4v*)(sm+DH1))[tid] = ldg16B((const f4v*)(ws + WS_H1 + wp*SLOT + b*256u) + tid);
        float plog = 0.f;
        if (tid < TENC){
          float s = 0.f;
          #pragma unroll
          for (int jj = 0; jj < PL; jj++){ int q = tid - jj; if (q >= 0) s += sm[DPR+jj]*sm[DAL+q]; }
          plog = logf(fmaxf(s, 1e-6f));
          #pragma unroll
          for (int c = 0; c < SF; c++){
            float s2 = 0.f;
            #pragma unroll
            for (int k = 0; k < SK; k++){ int q = tid + k - 10; if (q >= 0 && q < TENC) s2 += sm[DFF + c*SK + k]*sm[DAL+q]; }
            sm[DFS + c*TENC + tid] = s2;
          }
        }
        __syncthreads();
        if (tid < AD){
          float a = sm[DWB+tid];
          for (int k = 0; k < 256; k++) a += sm[DH1+k]*sm[DQW + k*AD + tid];
          sm[DQS+tid] = tanhf(a);
        }
        __syncthreads();
        if (tid < DF*DK){
          const float* attVT = ws + WS_ATTVT;
          float a = 0.f;
          for (int k = 0; k < AD; k++) a += sm[DQS+k]*attVT[k*(DF*DK) + tid];
          sm[DGS+tid] = a;
        }
        __syncthreads();
        if (tid < TENC){
          float g[DF];
          #pragma unroll
          for (int c = 0; c < DF; c++){
            float s = 0.f;
            #pragma unroll
            for (int k = 0; k < DK; k++){
              int q2 = tid + k - 10;
              if (q2 >= 0 && q2 < TENC) s += sm[DAL+q2]*sm[DGS + c*DK + k];
            }
            g[c] = s;
          }
          float pp = 0.f;
          for (int h = 0; h < AD; h++){
            float u = sm[DTB+h];
            #pragma unroll
            for (int s2 = 0; s2 < SF; s2++) u += sm[DUU + h*SF + s2]*sm[DFS + s2*TENC + tid];
            #pragma unroll
            for (int c = 0; c < DF; c++) u += sm[DTT + h*DF + c]*g[c];
            pp += sm[DVV+h]*tanh_fast(u);
          }
          sm[DES+tid] = pp + plog;
        }
        __syncthreads();
        float ex;
        {
          float v = (tid < TENC) ? sm[DES+tid] : -3.0e38f;
          for (int o = 1; o < 64; o <<= 1) v = fmaxf(v, __shfl_xor(v, o));
          if ((tid & 63) == 0) sm[DRB + (tid>>6)] = v;
          __syncthreads();
          if (tid == 0){ sm[DRB+4] = fmaxf(fmaxf(sm[DRB],sm[DRB+1]), fmaxf(sm[DRB+2],sm[DRB+3])); }
          __syncthreads();
          float m = sm[DRB+4];
          ex = (tid < TENC) ? expf(sm[DES+tid]-m) : 0.f;
          float sv = ex;
          for (int o = 1; o < 64; o <<= 1) sv += __shfl_xor(sv, o);
          __syncthreads();
          if ((tid & 63) == 0) sm[DRB + (tid>>6)] = sv;
          __syncthreads();
          if (tid == 0){ sm[DRB+5] = 1.f/(sm[DRB]+sm[DRB+1]+sm[DRB+2]+sm[DRB+3]); }
          __syncthreads();
          float inv = sm[DRB+5];
          if (tid < TENC){
            float a = ex*inv;
            sm[DAL+tid] = a;
            out[1024000 + b*TENC*STEPS + tid*STEPS + t] = a;
          }
        }
        __syncthreads();
        {
          float a0=0.f,a1=0.f,a2=0.f,a3=0.f;
          const float* mb = memory + (unsigned)b*TENC*MEM + tid;
          for (int p = 0; p < TENC; p += 4){
            a0 += sm[DAL+p  ]*mb[(p  )*MEM];
            a1 += sm[DAL+p+1]*mb[(p+1)*MEM];
            a2 += sm[DAL+p+2]*mb[(p+2)*MEM];
            a3 += sm[DAL+p+3]*mb[(p+3)*MEM];
          }
          stg4B(&ws[WS_CTX2 + wp*SLOT + b*256u + tid], (a0+a1)+(a2+a3));
        }
      }
    } else if (blk >= 96 && blk < 106){
      if (t >= 1){
        const int p = blk - 96;
        const int bb = tid >> 3, k0 = (tid & 7)*32;
        {
          const float* h2b = ws + WS_H2   + rp*SLOT + bb*256u + k0;
          const float* cxb = ws + WS_CTX2 + rp*SLOT + bb*256u + k0;
          f4v r[4];
          f4v* dh = (f4v*)(sm + PHC + bb*516 + k0);
          ldg64B(r, (const f4v*)h2b);        dh[0]=r[0]; dh[1]=r[1]; dh[2]=r[2]; dh[3]=r[3];
          ldg64B(r, (const f4v*)(h2b + 16)); dh[4]=r[0]; dh[5]=r[1]; dh[6]=r[2]; dh[7]=r[3];
          f4v* dc = (f4v*)(sm + PHC + bb*516 + 256 + k0);
          ldg64B(r, (const f4v*)cxb);        dc[0]=r[0]; dc[1]=r[1]; dc[2]=r[2]; dc[3]=r[3];
          ldg64B(r, (const f4v*)(cxb + 16)); dc[4]=r[0]; dc[5]=r[1]; dc[6]=r[2]; dc[7]=r[3];
        }
        __syncthreads();
        #pragma unroll
        for (int oo = 0; oo < 2; oo++){
          const int o = tid + oo*256;
          const int b = o >> 4, cl = o & 15;
          const int col = 16*p + cl;
          float acc = acb[col];
          const float* hc = sm + PHC + b*516;
          const float* wv = sm + PW + cl*520;
          for (int k = 0; k < 512; k += 4){
            float4 h4 = *(const float4*)(hc + k);
            float4 w4 = *(const float4*)(wv + k);
            acc += h4.x*w4.x + h4.y*w4.y + h4.z*w4.z + h4.w*w4.w;
          }
          out[(unsigned)b*NMELS*TMELS + (col>>1)*TMELS + 2*(t-1) + (col&1)] = acc;
        }
        __syncthreads();
      }
    }
    gridbar(bar, blk, bar_it++);
  }
}

extern "C" void kernel_launch(void* const* d_in, const int* in_sizes, int n_in,
                              void* d_out, int out_size, void* d_ws, size_t ws_size,
                              hipStream_t stream) {
  (void)in_sizes; (void)n_in; (void)out_size; (void)ws_size;
  const float* mels   = (const float*)d_in[0];
  const float* memory = (const float*)d_in[1];
  const float* pre_W1 = (const float*)d_in[2];
  const float* pre_b1 = (const float*)d_in[3];
  const float* pre_W2 = (const float*)d_in[4];
  const float* pre_b2 = (const float*)d_in[5];
  const float* al_Wih = (const float*)d_in[6];
  const float* al_Whh = (const float*)d_in[7];
  const float* al_bih = (const float*)d_in[8];
  const float* al_bhh = (const float*)d_in[9];
  const float* att_W  = (const float*)d_in[10];
  const float* att_Wb = (const float*)d_in[11];
  const float* att_V  = (const float*)d_in[12];
  const float* att_F  = (const float*)d_in[13];
  const float* att_U  = (const float*)d_in[14];
  const float* att_T  = (const float*)d_in[15];
  const float* att_Tb = (const float*)d_in[16];
  const float* att_v  = (const float*)d_in[17];
  const float* prior  = (const float*)d_in[18];
  const float* dl_Wih = (const float*)d_in[19];
  const float* dl_Whh = (const float*)d_in[20];
  const float* dl_bih = (const float*)d_in[21];
  const float* dl_bhh = (const float*)d_in[22];
  const float* ac_W   = (const float*)d_in[23];
  const float* ac_b   = (const float*)d_in[24];
  float* ws  = (float*)d_ws;
  float* out = (float*)d_out;

  hipFuncSetAttribute((const void*)persist, hipFuncAttributeMaxDynamicSharedMemorySize, DYNB);

  auto TR = [&](const float* src, unsigned off, int R, int C){
    int n = R*C;
    trk<<<dim3((n+255)/256), dim3(256), 0, stream>>>(src, ws + off, R, C);
  };
  TR(al_Wih, WS_W640,              1024, 384);
  TR(al_Whh, WS_W640 + 384u*1024u, 1024, 256);
  TR(dl_Wih, WS_W768,              1024, 512);
  TR(dl_Whh, WS_W768 + 512u*1024u, 1024, 256);
  TR(att_W,  WS_ATTWT, 128, 256);
  TR(att_V,  WS_ATTVT, 168, 128);
  TR(pre_W1, WS_PW1T,  256, 80);
  TR(pre_W2, WS_PW2T,  128, 256);

  initk<<<dim3(BB), dim3(256), 0, stream>>>(ws);
  prenetk<<<dim3(STEPS), dim3(256), 0, stream>>>(mels, pre_b1, pre_b2, ws);

  persist<<<dim3(G_NBLK), dim3(256), DYNB, stream>>>(
      al_bih, al_bhh, dl_bih, dl_bhh, prior, att_F,
      att_Wb, att_U, att_T, att_Tb, att_v, memory,
      ac_W, ac_b, ws, out);
}

// Round 13
// 52497.382 us; speedup vs baseline: 1.7908x; 1.5345x over previous
//
#include <hip/hip_runtime.h>
#include <math.h>

#define BB 32
#define TENC 200
#define NMELS 80
#define TMELS 400
#define STEPS 200
#define MEM 256
#define PRE1N 256
#define PRE2N 128
#define AD 128
#define DK 21
#define DF 8
#define SK 21
#define SF 8
#define PL 11
#define BLK 1024

// workspace offsets (floats) — all read-only after the pack/transpose prologue
#define WS_P1    0u          // al_Wih k4-packed  [96][1024][4]
#define WS_P2    393216u     // al_Whh k4-packed  [64][1024][4]
#define WS_P3    655360u     // dl_Wih k4-packed  [128][1024][4]
#define WS_P4    1179648u    // dl_Whh k4-packed  [64][1024][4]
#define WS_P5    1441792u    // ac_W  k4-packed   [128][160][4]
#define WS_ATTWT 1523712u    // att_W^T  [256][128]
#define WS_ATTVT 1556480u    // att_V^T  [128][168]
#define WS_PW1T  1577984u    // pre_W1^T [80][256]
#define WS_PW2T  1598464u    // pre_W2^T [256][128]
#define WS_PRE2  1631232u    // prenet out [200][32][128]
// total 2,450,432 floats = 9.8 MB

__device__ __forceinline__ float sigm(float x){ return 1.f/(1.f+expf(-x)); }
__device__ __forceinline__ float tanh_fast(float x){
  float ax = fabsf(x);
  float z = __expf(-2.f*ax);
  float r = (1.f - z)/(1.f + z);
  return (x < 0.f) ? -r : r;
}

// transpose: src[R][C] -> dst[C][R]
__global__ __launch_bounds__(256) void trk(const float* __restrict__ s, float* __restrict__ d, int R, int C){
  int i = blockIdx.x*256 + threadIdx.x;
  if (i < R*C){ int r = i / C, c = i - r*C; d[c*R + r] = s[i]; }
}

// k4-pack: src[R][C] -> dst[(c>>2)*R*4 + r*4 + (c&3)]
__global__ __launch_bounds__(256) void pk4(const float* __restrict__ s, float* __restrict__ d, int R, int C){
  int i = blockIdx.x*256 + threadIdx.x;
  if (i < R*C){ int r = i / C, c = i - r*C; d[(unsigned)(c>>2)*(unsigned)R*4u + (unsigned)r*4u + (c&3)] = s[i]; }
}

// prenet for all 200 steps (round-5 verbatim; proven)
__global__ __launch_bounds__(256) void prenetk(const float* __restrict__ mels,
    const float* __restrict__ b1, const float* __restrict__ b2, float* __restrict__ ws){
  int t = blockIdx.x, tid = threadIdx.x;
  __shared__ float xS[BB*NMELS];
  __shared__ float p1S[BB*PRE1N];
  const float* W1T = ws + WS_PW1T;
  const float* W2T = ws + WS_PW2T;
  for (int i=tid;i<BB*NMELS;i+=256){
    int r = i/NMELS, k = i - r*NMELS;
    xS[i] = (t==0)?0.f : mels[r*NMELS*TMELS + k*TMELS + (2*t-1)];
  }
  __syncthreads();
  {
    float acc[BB];
    #pragma unroll
    for (int r=0;r<BB;r++) acc[r]=0.f;
    for (int k=0;k<NMELS;k++){
      float w = W1T[k*PRE1N + tid];
      #pragma unroll
      for (int r=0;r<BB;r++) acc[r] += xS[r*NMELS+k]*w;
    }
    float bb = b1[tid];
    #pragma unroll
    for (int r=0;r<BB;r++) p1S[r*PRE1N+tid] = fmaxf(acc[r]+bb, 0.f);
  }
  __syncthreads();
  if (tid < PRE2N){
    float acc[BB];
    #pragma unroll
    for (int r=0;r<BB;r++) acc[r]=0.f;
    for (int k=0;k<PRE1N;k++){
      float w = W2T[k*PRE2N + tid];
      #pragma unroll
      for (int r=0;r<BB;r++) acc[r] += p1S[r*PRE1N+k]*w;
    }
    float bb = b2[tid];
    #pragma unroll
    for (int r=0;r<BB;r++) ws[WS_PRE2 + ((unsigned)t*BB + r)*PRE2N + tid] = fmaxf(acc[r]+bb, 0.f);
  }
}

// ONE BLOCK PER BATCH ELEMENT. All recurrent state in LDS; no grid sync anywhere.
__global__ __launch_bounds__(BLK) void decoder(
    const float* __restrict__ albih, const float* __restrict__ albhh,
    const float* __restrict__ dlbih, const float* __restrict__ dlbhh,
    const float* __restrict__ prior, const float* __restrict__ attF,
    const float* __restrict__ attWb, const float* __restrict__ attU,
    const float* __restrict__ attT, const float* __restrict__ attTb,
    const float* __restrict__ attv, const float* __restrict__ memory,
    const float* __restrict__ acb, const float* __restrict__ ws,
    float* __restrict__ out){
  const int b = blockIdx.x, tid = threadIdx.x;
  __shared__ float xvS[384];
  __shared__ float h1S[256], c1S[256], h2S[256], c2S[256], ctxS[256];
  __shared__ float alS[TENC], pS[TENC], eS[TENC];
  __shared__ float gat[1024], part[1024];
  __shared__ float qS[AD], GS[DF*DK];
  __shared__ float fS[SF*TENC];
  __shared__ float uS[AD*SF], tS2[AD*DF], tbS[AD], vS[AD];
  __shared__ float wFS[SF*SK], prS[PL];
  __shared__ float rb[17];

  // ---- one-time init (all arrays fully covered; strided loops for >range arrays) ----
  if (tid < 256){ h1S[tid]=0.f; c1S[tid]=0.f; h2S[tid]=0.f; c2S[tid]=0.f; ctxS[tid]=0.f; }
  if (tid < TENC) alS[tid] = (tid==0)?1.f:0.f;
  if (tid >= 256 && tid < 256+AD){ tbS[tid-256] = attTb[tid-256]; vS[tid-256] = attv[tid-256]; }
  if (tid >= 384 && tid < 384+SF*SK) wFS[tid-384] = attF[tid-384];
  if (tid >= 576 && tid < 576+PL)    prS[tid-576] = prior[tid-576];
  for (int i = tid; i < AD*SF; i += BLK) uS[i]  = attU[i];
  for (int i = tid; i < AD*DF; i += BLK) tS2[i] = attT[i];
  __syncthreads();

  const float* P1 = ws + WS_P1;
  const float* P2 = ws + WS_P2;
  const float* P3 = ws + WS_P3;
  const float* P4 = ws + WS_P4;
  const float* P5 = ws + WS_P5;
  const float* attWT = ws + WS_ATTWT;
  const float* attVT = ws + WS_ATTVT;

  for (int t = 0; t < STEPS; ++t){
    // 1. xv = [ctx(256), pre(128)]
    if (tid < 256) xvS[tid] = ctxS[tid];
    else if (tid < 384) xvS[tid] = ws[WS_PRE2 + ((unsigned)t*BB + b)*PRE2N + (tid-256)];
    __syncthreads();
    // 2. LSTM1 gates: gat[j] = bias + Wih.[ctx,pre] + Whh.h1
    {
      float acc = albih[tid] + albhh[tid];
      #pragma unroll 4
      for (int kk = 0; kk < 96; kk++){
        float4 w = *(const float4*)(P1 + (unsigned)kk*4096u + tid*4u);
        acc += w.x*xvS[4*kk] + w.y*xvS[4*kk+1] + w.z*xvS[4*kk+2] + w.w*xvS[4*kk+3];
      }
      #pragma unroll 4
      for (int kk = 0; kk < 64; kk++){
        float4 w = *(const float4*)(P2 + (unsigned)kk*4096u + tid*4u);
        acc += w.x*h1S[4*kk] + w.y*h1S[4*kk+1] + w.z*h1S[4*kk+2] + w.w*h1S[4*kk+3];
      }
      gat[tid] = acc;
    }
    __syncthreads();
    // 3. LSTM1 state update
    if (tid < 256){
      float gi=gat[tid], gf=gat[256+tid], gg=gat[512+tid], go=gat[768+tid];
      float c = sigm(gf)*c1S[tid] + sigm(gi)*tanhf(gg);
      c1S[tid] = c;
      h1S[tid] = sigm(go)*tanhf(c);
    }
    __syncthreads();
    // 4. q-partials (tid<512) || prior+static convs on align_{t-1} (tid in [512,712))
    if (tid < 512){
      const int quarter = tid >> 7, a = tid & 127;
      float s = 0.f;
      for (int k = 64*quarter; k < 64*quarter+64; k++) s += h1S[k]*attWT[k*AD + a];
      part[tid] = s;
    } else if (tid < 512+TENC){
      const int pos = tid - 512;
      float s = 0.f;
      #pragma unroll
      for (int jj = 0; jj < PL; jj++){ int q = pos - jj; if (q >= 0) s += prS[jj]*alS[q]; }
      pS[pos] = logf(fmaxf(s, 1e-6f));
      #pragma unroll
      for (int c = 0; c < SF; c++){
        float s2 = 0.f;
        #pragma unroll
        for (int k = 0; k < SK; k++){ int q = pos + k - 10; if (q>=0 && q<TENC) s2 += wFS[c*SK+k]*alS[q]; }
        fS[c*TENC + pos] = s2;
      }
    }
    __syncthreads();
    // 5. q = tanh
    if (tid < AD) qS[tid] = tanhf(attWb[tid] + part[tid] + part[128+tid] + part[256+tid] + part[384+tid]);
    __syncthreads();
    // 6. G = attV @ q
    if (tid < DF*DK){
      float a = 0.f;
      for (int k = 0; k < AD; k++) a += qS[k]*attVT[k*(DF*DK) + tid];
      GS[tid] = a;
    }
    __syncthreads();
    // 7. e[pos] = v . tanh(U f + T g + Tb) + p   (4 threads / pos)
    if (tid < 4*TENC){
      const int pos = tid >> 2, qr = tid & 3;
      float g[DF];
      #pragma unroll
      for (int c=0;c<DF;c++){
        float s=0.f;
        #pragma unroll
        for (int k=0;k<DK;k++){
          int q2 = pos + k - 10;
          if (q2>=0 && q2<TENC) s += alS[q2]*GS[c*DK+k];
        }
        g[c]=s;
      }
      float pp = 0.f;
      for (int h = qr*32; h < qr*32+32; h++){
        float u = tbS[h];
        #pragma unroll
        for (int s2=0;s2<SF;s2++) u += uS[h*SF+s2]*fS[s2*TENC+pos];
        #pragma unroll
        for (int c=0;c<DF;c++) u += tS2[h*DF+c]*g[c];
        pp += vS[h]*tanh_fast(u);
      }
      pp += __shfl_xor(pp,1);
      pp += __shfl_xor(pp,2);
      if (qr==0) eS[pos] = pp + pS[pos];
    }
    __syncthreads();
    // 8. softmax over 200
    float ex;
    {
      float v = (tid<TENC)? eS[tid] : -3.0e38f;
      for (int o=1;o<64;o<<=1) v = fmaxf(v, __shfl_xor(v,o));
      if ((tid&63)==0) rb[tid>>6] = v;
      __syncthreads();
      if (tid==0){ float m=rb[0]; for(int w=1;w<16;w++) m=fmaxf(m,rb[w]); rb[16]=m; }
      __syncthreads();
      float m = rb[16];
      ex = (tid<TENC)? expf(eS[tid]-m) : 0.f;
      float sv = ex;
      for (int o=1;o<64;o<<=1) sv += __shfl_xor(sv,o);
      __syncthreads();
      if ((tid&63)==0) rb[tid>>6] = sv;
      __syncthreads();
      if (tid==0){ float s=0.f; for(int w=0;w<16;w++) s+=rb[w]; rb[16]=1.f/s; }
      __syncthreads();
      float inv = rb[16];
      if (tid<TENC){
        float a = ex*inv;
        alS[tid] = a;
        out[1024000 + b*TENC*STEPS + tid*STEPS + t] = a;
      }
    }
    __syncthreads();
    // 9. ctx = align @ memory[b]
    {
      int grp = tid >> 8, j = tid & 255;
      float a=0.f;
      for (int p=grp*50; p<grp*50+50; p++) a += alS[p]*memory[((unsigned)b*TENC+p)*MEM + j];
      part[grp*256+j] = a;
    }
    __syncthreads();
    if (tid < 256) ctxS[tid] = part[tid]+part[256+tid]+part[512+tid]+part[768+tid];
    __syncthreads();
    // 10. LSTM2 gates: bias + Wih.[h1,ctx] + Whh.h2
    {
      float acc = dlbih[tid] + dlbhh[tid];
      #pragma unroll 4
      for (int kk = 0; kk < 64; kk++){
        float4 w = *(const float4*)(P3 + (unsigned)kk*4096u + tid*4u);
        acc += w.x*h1S[4*kk] + w.y*h1S[4*kk+1] + w.z*h1S[4*kk+2] + w.w*h1S[4*kk+3];
      }
      #pragma unroll 4
      for (int kk = 64; kk < 128; kk++){
        float4 w = *(const float4*)(P3 + (unsigned)kk*4096u + tid*4u);
        int k0 = 4*kk - 256;
        acc += w.x*ctxS[k0] + w.y*ctxS[k0+1] + w.z*ctxS[k0+2] + w.w*ctxS[k0+3];
      }
      #pragma unroll 4
      for (int kk = 0; kk < 64; kk++){
        float4 w = *(const float4*)(P4 + (unsigned)kk*4096u + tid*4u);
        acc += w.x*h2S[4*kk] + w.y*h2S[4*kk+1] + w.z*h2S[4*kk+2] + w.w*h2S[4*kk+3];
      }
      gat[tid] = acc;
    }
    __syncthreads();
    // 11. LSTM2 state update
    if (tid < 256){
      float gi=gat[tid], gf=gat[256+tid], gg=gat[512+tid], go=gat[768+tid];
      float c = sigm(gf)*c2S[tid] + sigm(gi)*tanhf(gg);
      c2S[tid] = c;
      h2S[tid] = sigm(go)*tanhf(c);
    }
    __syncthreads();
    // 12. acoustic projection: 4 threads / output col over K=512 [h2,ctx]
    if (tid < 640){
      const int col = tid >> 2, q = tid & 3;
      float acc = 0.f;
      for (int kk = q*32; kk < q*32+32; kk++){
        float4 w = *(const float4*)(P5 + (unsigned)kk*640u + col*4u);
        int k = 4*kk;
        if (k < 256) acc += w.x*h2S[k] + w.y*h2S[k+1] + w.z*h2S[k+2] + w.w*h2S[k+3];
        else { int k0=k-256; acc += w.x*ctxS[k0] + w.y*ctxS[k0+1] + w.z*ctxS[k0+2] + w.w*ctxS[k0+3]; }
      }
      acc += __shfl_xor(acc,1);
      acc += __shfl_xor(acc,2);
      if (q==0){
        const int m = col >> 1, r = col & 1;
        out[(unsigned)b*NMELS*TMELS + m*TMELS + 2*t + r] = acc + acb[col];
      }
    }
    __syncthreads();
  }
}

extern "C" void kernel_launch(void* const* d_in, const int* in_sizes, int n_in,
                              void* d_out, int out_size, void* d_ws, size_t ws_size,
                              hipStream_t stream) {
  (void)in_sizes; (void)n_in; (void)out_size; (void)ws_size;
  const float* mels   = (const float*)d_in[0];
  const float* memory = (const float*)d_in[1];
  const float* pre_W1 = (const float*)d_in[2];
  const float* pre_b1 = (const float*)d_in[3];
  const float* pre_W2 = (const float*)d_in[4];
  const float* pre_b2 = (const float*)d_in[5];
  const float* al_Wih = (const float*)d_in[6];
  const float* al_Whh = (const float*)d_in[7];
  const float* al_bih = (const float*)d_in[8];
  const float* al_bhh = (const float*)d_in[9];
  const float* att_W  = (const float*)d_in[10];
  const float* att_Wb = (const float*)d_in[11];
  const float* att_V  = (const float*)d_in[12];
  const float* att_F  = (const float*)d_in[13];
  const float* att_U  = (const float*)d_in[14];
  const float* att_T  = (const float*)d_in[15];
  const float* att_Tb = (const float*)d_in[16];
  const float* att_v  = (const float*)d_in[17];
  const float* prior  = (const float*)d_in[18];
  const float* dl_Wih = (const float*)d_in[19];
  const float* dl_Whh = (const float*)d_in[20];
  const float* dl_bih = (const float*)d_in[21];
  const float* dl_bhh = (const float*)d_in[22];
  const float* ac_W   = (const float*)d_in[23];
  const float* ac_b   = (const float*)d_in[24];
  float* ws  = (float*)d_ws;
  float* out = (float*)d_out;

  auto TR = [&](const float* src, unsigned off, int R, int C){
    int n = R*C;
    trk<<<dim3((n+255)/256), dim3(256), 0, stream>>>(src, ws + off, R, C);
  };
  auto PK = [&](const float* src, unsigned off, int R, int C){
    int n = R*C;
    pk4<<<dim3((n+255)/256), dim3(256), 0, stream>>>(src, ws + off, R, C);
  };
  PK(al_Wih, WS_P1, 1024, 384);
  PK(al_Whh, WS_P2, 1024, 256);
  PK(dl_Wih, WS_P3, 1024, 512);
  PK(dl_Whh, WS_P4, 1024, 256);
  PK(ac_W,   WS_P5, 160, 512);
  TR(att_W,  WS_ATTWT, 128, 256);
  TR(att_V,  WS_ATTVT, 168, 128);
  TR(pre_W1, WS_PW1T,  256, 80);
  TR(pre_W2, WS_PW2T,  128, 256);

  prenetk<<<dim3(STEPS), dim3(256), 0, stream>>>(mels, pre_b1, pre_b2, ws);

  decoder<<<dim3(BB), dim3(BLK), 0, stream>>>(
      al_bih, al_bhh, dl_bih, dl_bhh, prior, att_F,
      att_Wb, att_U, att_T, att_Tb, att_v, memory,
      ac_b, ws, out);
}

// Round 16
// 39875.015 us; speedup vs baseline: 2.3577x; 1.3165x over previous
//
#include <hip/hip_runtime.h>
#include <math.h>

#define BB 32
#define TENC 200
#define NMELS 80
#define TMELS 400
#define STEPS 200
#define MEM 256
#define PRE1N 256
#define PRE2N 128
#define AD 128
#define DK 21
#define DF 8
#define SK 21
#define SF 8
#define PL 11
#define BLK 1024

// bf16 k4-packed weights live at ws[0..761856) floats viewed as ushort[1523712]:
#define HP1 0u          // al_Wih [96][1024][4] bf16
#define HP2 393216u     // al_Whh [64][1024][4]
#define HP3 655360u     // dl_Wih [128][1024][4]
#define HP4 1179648u    // dl_Whh [64][1024][4]
#define HP5 1441792u    // ac_W  [128][160][4]   (end 1523712 ushorts)
// fp32 regions (float offsets):
#define WS_ATTWT 761856u   // att_W^T [256][128]
#define WS_ATTVT 794624u   // att_V^T [128][168]
#define WS_PW1T  816128u   // pre_W1^T [80][256]
#define WS_PW2T  836608u   // pre_W2^T [256][128]
#define WS_PRE2  869376u   // prenet out [200][32][128]
// total 1,688,576 floats = 6.75 MB

__device__ __forceinline__ float sigm(float x){ return 1.f/(1.f+expf(-x)); }
__device__ __forceinline__ float tanh_fast(float x){
  float ax = fabsf(x);
  float z = __expf(-2.f*ax);
  float r = (1.f - z)/(1.f + z);
  return (x < 0.f) ? -r : r;
}

// transpose: src[R][C] -> dst[C][R]
__global__ __launch_bounds__(256) void trk(const float* __restrict__ s, float* __restrict__ d, int R, int C){
  int i = blockIdx.x*256 + threadIdx.x;
  if (i < R*C){ int r = i / C, c = i - r*C; d[c*R + r] = s[i]; }
}

// k4-pack to bf16 (RNE): src[R][C] fp32 -> dst[(c>>2)*R*4 + r*4 + (c&3)] bf16
__global__ __launch_bounds__(256) void pk4h(const float* __restrict__ s, unsigned short* __restrict__ d, int R, int C){
  int i = blockIdx.x*256 + threadIdx.x;
  if (i < R*C){
    int r = i / C, c = i - r*C;
    unsigned u = __float_as_uint(s[i]);
    unsigned short h = (unsigned short)((u + 0x7fffu + ((u>>16)&1u)) >> 16);
    d[(unsigned)(c>>2)*(unsigned)R*4u + (unsigned)r*4u + (c&3)] = h;
  }
}

// prenet for all 200 steps (proven)
__global__ __launch_bounds__(256) void prenetk(const float* __restrict__ mels,
    const float* __restrict__ b1, const float* __restrict__ b2, float* __restrict__ ws){
  int t = blockIdx.x, tid = threadIdx.x;
  __shared__ float xS[BB*NMELS];
  __shared__ float p1S[BB*PRE1N];
  const float* W1T = ws + WS_PW1T;
  const float* W2T = ws + WS_PW2T;
  for (int i=tid;i<BB*NMELS;i+=256){
    int r = i/NMELS, k = i - r*NMELS;
    xS[i] = (t==0)?0.f : mels[r*NMELS*TMELS + k*TMELS + (2*t-1)];
  }
  __syncthreads();
  {
    float acc[BB];
    #pragma unroll
    for (int r=0;r<BB;r++) acc[r]=0.f;
    for (int k=0;k<NMELS;k++){
      float w = W1T[k*PRE1N + tid];
      #pragma unroll
      for (int r=0;r<BB;r++) acc[r] += xS[r*NMELS+k]*w;
    }
    float bb = b1[tid];
    #pragma unroll
    for (int r=0;r<BB;r++) p1S[r*PRE1N+tid] = fmaxf(acc[r]+bb, 0.f);
  }
  __syncthreads();
  if (tid < PRE2N){
    float acc[BB];
    #pragma unroll
    for (int r=0;r<BB;r++) acc[r]=0.f;
    for (int k=0;k<PRE1N;k++){
      float w = W2T[k*PRE2N + tid];
      #pragma unroll
      for (int r=0;r<BB;r++) acc[r] += p1S[r*PRE1N+k]*w;
    }
    float bb = b2[tid];
    #pragma unroll
    for (int r=0;r<BB;r++) ws[WS_PRE2 + ((unsigned)t*BB + r)*PRE2N + tid] = fmaxf(acc[r]+bb, 0.f);
  }
}

// ONE BLOCK PER BATCH ELEMENT. All recurrent state in LDS; no grid sync.
// Weights bf16-packed (3.05 MB working set -> fits per-XCD L2).
__global__ __launch_bounds__(BLK) void decoder(
    const float* __restrict__ albih, const float* __restrict__ albhh,
    const float* __restrict__ dlbih, const float* __restrict__ dlbhh,
    const float* __restrict__ prior, const float* __restrict__ attF,
    const float* __restrict__ attWb, const float* __restrict__ attU,
    const float* __restrict__ attT, const float* __restrict__ attTb,
    const float* __restrict__ attv, const float* __restrict__ memory,
    const float* __restrict__ acb, const float* __restrict__ ws,
    float* __restrict__ out){
  const int b = blockIdx.x, tid = threadIdx.x;
  __shared__ float xvS[384];
  __shared__ float h1S[256], c1S[256], h2S[256], c2S[256], ctxS[256];
  __shared__ float alS[TENC], pS[TENC], eS[TENC];
  __shared__ float gat[1024], part[1024];
  __shared__ float qS[AD], GS[DF*DK];
  __shared__ float fS[SF*TENC];
  __shared__ float uS[AD*SF], tS2[AD*DF], tbS[AD], vS[AD];
  __shared__ float wFS[SF*SK], prS[PL];
  __shared__ float rb[17];

  // ---- one-time init ----
  if (tid < 256){ h1S[tid]=0.f; c1S[tid]=0.f; h2S[tid]=0.f; c2S[tid]=0.f; ctxS[tid]=0.f; }
  if (tid < TENC) alS[tid] = (tid==0)?1.f:0.f;
  if (tid >= 256 && tid < 256+AD){ tbS[tid-256] = attTb[tid-256]; vS[tid-256] = attv[tid-256]; }
  if (tid >= 384 && tid < 384+SF*SK) wFS[tid-384] = attF[tid-384];
  if (tid >= 576 && tid < 576+PL)    prS[tid-576] = prior[tid-576];
  for (int i = tid; i < AD*SF; i += BLK) uS[i]  = attU[i];
  for (int i = tid; i < AD*DF; i += BLK) tS2[i] = attT[i];
  __syncthreads();

  const unsigned short* hw = (const unsigned short*)ws;
  const unsigned short* P1 = hw + HP1;
  const unsigned short* P2 = hw + HP2;
  const unsigned short* P3 = hw + HP3;
  const unsigned short* P4 = hw + HP4;
  const unsigned short* P5 = hw + HP5;
  const float* attWT = ws + WS_ATTWT;
  const float* attVT = ws + WS_ATTVT;

  for (int t = 0; t < STEPS; ++t){
    // 1. xv = [ctx(256), pre(128)]
    if (tid < 256) xvS[tid] = ctxS[tid];
    else if (tid < 384) xvS[tid] = ws[WS_PRE2 + ((unsigned)t*BB + b)*PRE2N + (tid-256)];
    __syncthreads();
    // 2. LSTM1 gates
    {
      float acc = albih[tid] + albhh[tid];
      #pragma unroll 4
      for (int kk = 0; kk < 96; kk++){
        uint2 wv = *(const uint2*)(P1 + (unsigned)kk*4096u + tid*4u);
        float w0 = __uint_as_float(wv.x << 16);
        float w1 = __uint_as_float(wv.x & 0xffff0000u);
        float w2 = __uint_as_float(wv.y << 16);
        float w3 = __uint_as_float(wv.y & 0xffff0000u);
        acc += w0*xvS[4*kk] + w1*xvS[4*kk+1] + w2*xvS[4*kk+2] + w3*xvS[4*kk+3];
      }
      #pragma unroll 4
      for (int kk = 0; kk < 64; kk++){
        uint2 wv = *(const uint2*)(P2 + (unsigned)kk*4096u + tid*4u);
        float w0 = __uint_as_float(wv.x << 16);
        float w1 = __uint_as_float(wv.x & 0xffff0000u);
        float w2 = __uint_as_float(wv.y << 16);
        float w3 = __uint_as_float(wv.y & 0xffff0000u);
        acc += w0*h1S[4*kk] + w1*h1S[4*kk+1] + w2*h1S[4*kk+2] + w3*h1S[4*kk+3];
      }
      gat[tid] = acc;
    }
    __syncthreads();
    // 3. LSTM1 state update
    if (tid < 256){
      float gi=gat[tid], gf=gat[256+tid], gg=gat[512+tid], go=gat[768+tid];
      float c = sigm(gf)*c1S[tid] + sigm(gi)*tanhf(gg);
      c1S[tid] = c;
      h1S[tid] = sigm(go)*tanhf(c);
    }
    __syncthreads();
    // 4. q-partials (tid<512) || prior+static convs on align_{t-1} (tid in [512,712))
    if (tid < 512){
      const int quarter = tid >> 7, a = tid & 127;
      float s = 0.f;
      for (int k = 64*quarter; k < 64*quarter+64; k++) s += h1S[k]*attWT[k*AD + a];
      part[tid] = s;
    } else if (tid < 512+TENC){
      const int pos = tid - 512;
      float s = 0.f;
      #pragma unroll
      for (int jj = 0; jj < PL; jj++){ int q = pos - jj; if (q >= 0) s += prS[jj]*alS[q]; }
      pS[pos] = logf(fmaxf(s, 1e-6f));
      #pragma unroll
      for (int c = 0; c < SF; c++){
        float s2 = 0.f;
        #pragma unroll
        for (int k = 0; k < SK; k++){ int q = pos + k - 10; if (q>=0 && q<TENC) s2 += wFS[c*SK+k]*alS[q]; }
        fS[c*TENC + pos] = s2;
      }
    }
    __syncthreads();
    // 5. q = tanh
    if (tid < AD) qS[tid] = tanhf(attWb[tid] + part[tid] + part[128+tid] + part[256+tid] + part[384+tid]);
    __syncthreads();
    // 6. G = attV @ q
    if (tid < DF*DK){
      float a = 0.f;
      for (int k = 0; k < AD; k++) a += qS[k]*attVT[k*(DF*DK) + tid];
      GS[tid] = a;
    }
    __syncthreads();
    // 7. e[pos] = v . tanh(U f + T g + Tb) + p   (4 threads / pos)
    if (tid < 4*TENC){
      const int pos = tid >> 2, qr = tid & 3;
      float g[DF];
      #pragma unroll
      for (int c=0;c<DF;c++){
        float s=0.f;
        #pragma unroll
        for (int k=0;k<DK;k++){
          int q2 = pos + k - 10;
          if (q2>=0 && q2<TENC) s += alS[q2]*GS[c*DK+k];
        }
        g[c]=s;
      }
      float pp = 0.f;
      for (int h = qr*32; h < qr*32+32; h++){
        float u = tbS[h];
        #pragma unroll
        for (int s2=0;s2<SF;s2++) u += uS[h*SF+s2]*fS[s2*TENC+pos];
        #pragma unroll
        for (int c=0;c<DF;c++) u += tS2[h*DF+c]*g[c];
        pp += vS[h]*tanh_fast(u);
      }
      pp += __shfl_xor(pp,1);
      pp += __shfl_xor(pp,2);
      if (qr==0) eS[pos] = pp + pS[pos];
    }
    __syncthreads();
    // 8. softmax over 200
    float ex;
    {
      float v = (tid<TENC)? eS[tid] : -3.0e38f;
      for (int o=1;o<64;o<<=1) v = fmaxf(v, __shfl_xor(v,o));
      if ((tid&63)==0) rb[tid>>6] = v;
      __syncthreads();
      if (tid==0){ float m=rb[0]; for(int w=1;w<16;w++) m=fmaxf(m,rb[w]); rb[16]=m; }
      __syncthreads();
      float m = rb[16];
      ex = (tid<TENC)? expf(eS[tid]-m) : 0.f;
      float sv = ex;
      for (int o=1;o<64;o<<=1) sv += __shfl_xor(sv,o);
      __syncthreads();
      if ((tid&63)==0) rb[tid>>6] = sv;
      __syncthreads();
      if (tid==0){ float s=0.f; for(int w=0;w<16;w++) s+=rb[w]; rb[16]=1.f/s; }
      __syncthreads();
      float inv = rb[16];
      if (tid<TENC){
        float a = ex*inv;
        alS[tid] = a;
        out[1024000 + b*TENC*STEPS + tid*STEPS + t] = a;
      }
    }
    __syncthreads();
    // 9. ctx = align @ memory[b]
    {
      int grp = tid >> 8, j = tid & 255;
      float a=0.f;
      for (int p=grp*50; p<grp*50+50; p++) a += alS[p]*memory[((unsigned)b*TENC+p)*MEM + j];
      part[grp*256+j] = a;
    }
    __syncthreads();
    if (tid < 256) ctxS[tid] = part[tid]+part[256+tid]+part[512+tid]+part[768+tid];
    __syncthreads();
    // 10. LSTM2 gates
    {
      float acc = dlbih[tid] + dlbhh[tid];
      #pragma unroll 4
      for (int kk = 0; kk < 64; kk++){
        uint2 wv = *(const uint2*)(P3 + (unsigned)kk*4096u + tid*4u);
        float w0 = __uint_as_float(wv.x << 16);
        float w1 = __uint_as_float(wv.x & 0xffff0000u);
        float w2 = __uint_as_float(wv.y << 16);
        float w3 = __uint_as_float(wv.y & 0xffff0000u);
        acc += w0*h1S[4*kk] + w1*h1S[4*kk+1] + w2*h1S[4*kk+2] + w3*h1S[4*kk+3];
      }
      #pragma unroll 4
      for (int kk = 64; kk < 128; kk++){
        uint2 wv = *(const uint2*)(P3 + (unsigned)kk*4096u + tid*4u);
        float w0 = __uint_as_float(wv.x << 16);
        float w1 = __uint_as_float(wv.x & 0xffff0000u);
        float w2 = __uint_as_float(wv.y << 16);
        float w3 = __uint_as_float(wv.y & 0xffff0000u);
        int k0 = 4*kk - 256;
        acc += w0*ctxS[k0] + w1*ctxS[k0+1] + w2*ctxS[k0+2] + w3*ctxS[k0+3];
      }
      #pragma unroll 4
      for (int kk = 0; kk < 64; kk++){
        uint2 wv = *(const uint2*)(P4 + (unsigned)kk*4096u + tid*4u);
        float w0 = __uint_as_float(wv.x << 16);
        float w1 = __uint_as_float(wv.x & 0xffff0000u);
        float w2 = __uint_as_float(wv.y << 16);
        float w3 = __uint_as_float(wv.y & 0xffff0000u);
        acc += w0*h2S[4*kk] + w1*h2S[4*kk+1] + w2*h2S[4*kk+2] + w3*h2S[4*kk+3];
      }
      gat[tid] = acc;
    }
    __syncthreads();
    // 11. LSTM2 state update
    if (tid < 256){
      float gi=gat[tid], gf=gat[256+tid], gg=gat[512+tid], go=gat[768+tid];
      float c = sigm(gf)*c2S[tid] + sigm(gi)*tanhf(gg);
      c2S[tid] = c;
      h2S[tid] = sigm(go)*tanhf(c);
    }
    __syncthreads();
    // 12. acoustic projection: 4 threads / output col over K=512 [h2,ctx]
    if (tid < 640){
      const int col = tid >> 2, q = tid & 3;
      float acc = 0.f;
      for (int kk = q*32; kk < q*32+32; kk++){
        uint2 wv = *(const uint2*)(P5 + (unsigned)kk*640u + col*4u);
        float w0 = __uint_as_float(wv.x << 16);
        float w1 = __uint_as_float(wv.x & 0xffff0000u);
        float w2 = __uint_as_float(wv.y << 16);
        float w3 = __uint_as_float(wv.y & 0xffff0000u);
        int k = 4*kk;
        if (k < 256) acc += w0*h2S[k] + w1*h2S[k+1] + w2*h2S[k+2] + w3*h2S[k+3];
        else { int k0=k-256; acc += w0*ctxS[k0] + w1*ctxS[k0+1] + w2*ctxS[k0+2] + w3*ctxS[k0+3]; }
      }
      acc += __shfl_xor(acc,1);
      acc += __shfl_xor(acc,2);
      if (q==0){
        const int m = col >> 1, r = col & 1;
        out[(unsigned)b*NMELS*TMELS + m*TMELS + 2*t + r] = acc + acb[col];
      }
    }
    __syncthreads();
  }
}

extern "C" void kernel_launch(void* const* d_in, const int* in_sizes, int n_in,
                              void* d_out, int out_size, void* d_ws, size_t ws_size,
                              hipStream_t stream) {
  (void)in_sizes; (void)n_in; (void)out_size; (void)ws_size;
  const float* mels   = (const float*)d_in[0];
  const float* memory = (const float*)d_in[1];
  const float* pre_W1 = (const float*)d_in[2];
  const float* pre_b1 = (const float*)d_in[3];
  const float* pre_W2 = (const float*)d_in[4];
  const float* pre_b2 = (const float*)d_in[5];
  const float* al_Wih = (const float*)d_in[6];
  const float* al_Whh = (const float*)d_in[7];
  const float* al_bih = (const float*)d_in[8];
  const float* al_bhh = (const float*)d_in[9];
  const float* att_W  = (const float*)d_in[10];
  const float* att_Wb = (const float*)d_in[11];
  const float* att_V  = (const float*)d_in[12];
  const float* att_F  = (const float*)d_in[13];
  const float* att_U  = (const float*)d_in[14];
  const float* att_T  = (const float*)d_in[15];
  const float* att_Tb = (const float*)d_in[16];
  const float* att_v  = (const float*)d_in[17];
  const float* prior  = (const float*)d_in[18];
  const float* dl_Wih = (const float*)d_in[19];
  const float* dl_Whh = (const float*)d_in[20];
  const float* dl_bih = (const float*)d_in[21];
  const float* dl_bhh = (const float*)d_in[22];
  const float* ac_W   = (const float*)d_in[23];
  const float* ac_b   = (const float*)d_in[24];
  float* ws  = (float*)d_ws;
  unsigned short* hw = (unsigned short*)d_ws;
  float* out = (float*)d_out;

  auto TR = [&](const float* src, unsigned off, int R, int C){
    int n = R*C;
    trk<<<dim3((n+255)/256), dim3(256), 0, stream>>>(src, ws + off, R, C);
  };
  auto PKH = [&](const float* src, unsigned off_us, int R, int C){
    int n = R*C;
    pk4h<<<dim3((n+255)/256), dim3(256), 0, stream>>>(src, hw + off_us, R, C);
  };
  PKH(al_Wih, HP1, 1024, 384);
  PKH(al_Whh, HP2, 1024, 256);
  PKH(dl_Wih, HP3, 1024, 512);
  PKH(dl_Whh, HP4, 1024, 256);
  PKH(ac_W,   HP5, 160, 512);
  TR(att_W,  WS_ATTWT, 128, 256);
  TR(att_V,  WS_ATTVT, 168, 128);
  TR(pre_W1, WS_PW1T,  256, 80);
  TR(pre_W2, WS_PW2T,  128, 256);

  prenetk<<<dim3(STEPS), dim3(256), 0, stream>>>(mels, pre_b1, pre_b2, ws);

  decoder<<<dim3(BB), dim3(BLK), 0, stream>>>(
      al_bih, al_bhh, dl_bih, dl_bhh, prior, att_F,
      att_Wb, att_U, att_T, att_Tb, att_v, memory,
      ac_b, ws, out);
}

// Round 17
// 30707.428 us; speedup vs baseline: 3.0616x; 1.2985x over previous
//
#include <hip/hip_runtime.h>
#include <math.h>

#define BB 32
#define TENC 200
#define NMELS 80
#define TMELS 400
#define STEPS 200
#define MEM 256
#define PRE1N 256
#define PRE2N 128
#define AD 128
#define DK 21
#define DF 8
#define SK 21
#define SF 8
#define PL 11
#define BLK 1024

// bf16 8-wide-packed weights at ws[0..761856) floats = ushort[1523712]:
// layout: elem(k, col) at (k>>3)*R*8 + col*8 + (k&7)
#define HP1 0u          // al_Wih [48][1024][8] (K=384)
#define HP2 393216u     // al_Whh [32][1024][8] (K=256)
#define HP3 655360u     // dl_Wih [64][1024][8] (K=512)
#define HP4 1179648u    // dl_Whh [32][1024][8] (K=256)
#define HP5 1441792u    // ac_W  [64][160][8]  (K=512)  end 1523712
// fp32 regions (float offsets):
#define WS_ATTWT 761856u   // att_W^T [256][128]
#define WS_ATTVT 794624u   // att_V^T [128][168]
#define WS_PW1T  816128u   // pre_W1^T [80][256]
#define WS_PW2T  836608u   // pre_W2^T [256][128]
#define WS_PRE2  869376u   // prenet out [200][32][128]
// total 1,688,576 floats = 6.75 MB

__device__ __forceinline__ float sigm(float x){ return 1.f/(1.f+expf(-x)); }
__device__ __forceinline__ float tanh_fast(float x){
  float ax = fabsf(x);
  float z = __expf(-2.f*ax);
  float r = (1.f - z)/(1.f + z);
  return (x < 0.f) ? -r : r;
}

// transpose: src[R][C] -> dst[C][R]
__global__ __launch_bounds__(256) void trk(const float* __restrict__ s, float* __restrict__ d, int R, int C){
  int i = blockIdx.x*256 + threadIdx.x;
  if (i < R*C){ int r = i / C, c = i - r*C; d[c*R + r] = s[i]; }
}

// 8-wide-pack to bf16 (RNE): src[R][C] fp32 -> dst[(c>>3)*R*8 + r*8 + (c&7)] bf16
__global__ __launch_bounds__(256) void pk8h(const float* __restrict__ s, unsigned short* __restrict__ d, int R, int C){
  int i = blockIdx.x*256 + threadIdx.x;
  if (i < R*C){
    int r = i / C, c = i - r*C;
    unsigned u = __float_as_uint(s[i]);
    unsigned short h = (unsigned short)((u + 0x7fffu + ((u>>16)&1u)) >> 16);
    d[(unsigned)(c>>3)*(unsigned)R*8u + (unsigned)r*8u + (c&7)] = h;
  }
}

// prenet for all 200 steps (proven)
__global__ __launch_bounds__(256) void prenetk(const float* __restrict__ mels,
    const float* __restrict__ b1, const float* __restrict__ b2, float* __restrict__ ws){
  int t = blockIdx.x, tid = threadIdx.x;
  __shared__ float xS[BB*NMELS];
  __shared__ float p1S[BB*PRE1N];
  const float* W1T = ws + WS_PW1T;
  const float* W2T = ws + WS_PW2T;
  for (int i=tid;i<BB*NMELS;i+=256){
    int r = i/NMELS, k = i - r*NMELS;
    xS[i] = (t==0)?0.f : mels[r*NMELS*TMELS + k*TMELS + (2*t-1)];
  }
  __syncthreads();
  {
    float acc[BB];
    #pragma unroll
    for (int r=0;r<BB;r++) acc[r]=0.f;
    for (int k=0;k<NMELS;k++){
      float w = W1T[k*PRE1N + tid];
      #pragma unroll
      for (int r=0;r<BB;r++) acc[r] += xS[r*NMELS+k]*w;
    }
    float bb = b1[tid];
    #pragma unroll
    for (int r=0;r<BB;r++) p1S[r*PRE1N+tid] = fmaxf(acc[r]+bb, 0.f);
  }
  __syncthreads();
  if (tid < PRE2N){
    float acc[BB];
    #pragma unroll
    for (int r=0;r<BB;r++) acc[r]=0.f;
    for (int k=0;k<PRE1N;k++){
      float w = W2T[k*PRE2N + tid];
      #pragma unroll
      for (int r=0;r<BB;r++) acc[r] += p1S[r*PRE1N+k]*w;
    }
    float bb = b2[tid];
    #pragma unroll
    for (int r=0;r<BB;r++) ws[WS_PRE2 + ((unsigned)t*BB + r)*PRE2N + tid] = fmaxf(acc[r]+bb, 0.f);
  }
}

// unpack helper: 8 bf16 from uint4, FMA against 8 consecutive LDS floats into 4 accs
#define FMA8(wv, xp, a0, a1, a2, a3)                                              \
  a0 += __uint_as_float((wv).x << 16)*(xp)[0] + __uint_as_float((wv).x & 0xffff0000u)*(xp)[1]; \
  a1 += __uint_as_float((wv).y << 16)*(xp)[2] + __uint_as_float((wv).y & 0xffff0000u)*(xp)[3]; \
  a2 += __uint_as_float((wv).z << 16)*(xp)[4] + __uint_as_float((wv).z & 0xffff0000u)*(xp)[5]; \
  a3 += __uint_as_float((wv).w << 16)*(xp)[6] + __uint_as_float((wv).w & 0xffff0000u)*(xp)[7];

// ONE BLOCK PER BATCH ELEMENT. All recurrent state in LDS; no grid sync.
// Weights bf16 8-wide packed; uint4 loads, 4 accumulators; memory/pre2 nontemporal.
__global__ __launch_bounds__(BLK) void decoder(
    const float* __restrict__ albih, const float* __restrict__ albhh,
    const float* __restrict__ dlbih, const float* __restrict__ dlbhh,
    const float* __restrict__ prior, const float* __restrict__ attF,
    const float* __restrict__ attWb, const float* __restrict__ attU,
    const float* __restrict__ attT, const float* __restrict__ attTb,
    const float* __restrict__ attv, const float* __restrict__ memory,
    const float* __restrict__ acb, const float* __restrict__ ws,
    float* __restrict__ out){
  const int b = blockIdx.x, tid = threadIdx.x;
  __shared__ float preS[128];
  __shared__ float h1S[256], c1S[256], h2S[256], c2S[256], ctxS[256];
  __shared__ float alS[TENC], pS[TENC], eS[TENC];
  __shared__ float gat[1024], part[1024];
  __shared__ float qS[AD], GS[DF*DK];
  __shared__ float fS[SF*TENC];
  __shared__ float uS[AD*SF], tS2[AD*DF], tbS[AD], vS[AD];
  __shared__ float wFS[SF*SK], prS[PL];
  __shared__ float rb[17];

  // ---- one-time init ----
  if (tid < 256){ h1S[tid]=0.f; c1S[tid]=0.f; h2S[tid]=0.f; c2S[tid]=0.f; ctxS[tid]=0.f; }
  if (tid < TENC) alS[tid] = (tid==0)?1.f:0.f;
  if (tid >= 256 && tid < 256+AD){ tbS[tid-256] = attTb[tid-256]; vS[tid-256] = attv[tid-256]; }
  if (tid >= 384 && tid < 384+SF*SK) wFS[tid-384] = attF[tid-384];
  if (tid >= 576 && tid < 576+PL)    prS[tid-576] = prior[tid-576];
  for (int i = tid; i < AD*SF; i += BLK) uS[i]  = attU[i];
  for (int i = tid; i < AD*DF; i += BLK) tS2[i] = attT[i];
  __syncthreads();

  const unsigned short* hw = (const unsigned short*)ws;
  const unsigned short* P1 = hw + HP1;
  const unsigned short* P2 = hw + HP2;
  const unsigned short* P3 = hw + HP3;
  const unsigned short* P4 = hw + HP4;
  const unsigned short* P5 = hw + HP5;
  const float* attWT = ws + WS_ATTWT;
  const float* attVT = ws + WS_ATTVT;

  // hoist per-step-invariant scalars
  const float bias1 = albih[tid] + albhh[tid];
  const float bias2 = dlbih[tid] + dlbhh[tid];
  const float acbv  = (tid < 640) ? acb[tid >> 2] : 0.f;

  for (int t = 0; t < STEPS; ++t){
    // 1. stage prenet slice (ctx read directly from ctxS in phase 2)
    if (tid < 128) preS[tid] = __builtin_nontemporal_load(&ws[WS_PRE2 + ((unsigned)t*BB + b)*PRE2N + tid]);
    __syncthreads();
    // 2. LSTM1 gates: K = [ctx 256 | pre 128 | h1 256]
    {
      float a0 = bias1, a1 = 0.f, a2 = 0.f, a3 = 0.f;
      #pragma unroll 4
      for (int kk = 0; kk < 32; kk++){
        uint4 wv = *(const uint4*)(P1 + (unsigned)kk*8192u + tid*8u);
        const float* xp = ctxS + 8*kk;
        FMA8(wv, xp, a0, a1, a2, a3)
      }
      #pragma unroll 4
      for (int kk = 32; kk < 48; kk++){
        uint4 wv = *(const uint4*)(P1 + (unsigned)kk*8192u + tid*8u);
        const float* xp = preS + 8*kk - 256;
        FMA8(wv, xp, a0, a1, a2, a3)
      }
      #pragma unroll 4
      for (int kk = 0; kk < 32; kk++){
        uint4 wv = *(const uint4*)(P2 + (unsigned)kk*8192u + tid*8u);
        const float* xp = h1S + 8*kk;
        FMA8(wv, xp, a0, a1, a2, a3)
      }
      gat[tid] = (a0+a1)+(a2+a3);
    }
    __syncthreads();
    // 3. LSTM1 state update
    if (tid < 256){
      float gi=gat[tid], gf=gat[256+tid], gg=gat[512+tid], go=gat[768+tid];
      float c = sigm(gf)*c1S[tid] + sigm(gi)*tanhf(gg);
      c1S[tid] = c;
      h1S[tid] = sigm(go)*tanhf(c);
    }
    __syncthreads();
    // 4. q-partials (tid<512) || prior+static convs on align_{t-1} (tid in [512,712))
    if (tid < 512){
      const int quarter = tid >> 7, a = tid & 127;
      float s = 0.f;
      for (int k = 64*quarter; k < 64*quarter+64; k++) s += h1S[k]*attWT[k*AD + a];
      part[tid] = s;
    } else if (tid < 512+TENC){
      const int pos = tid - 512;
      float s = 0.f;
      #pragma unroll
      for (int jj = 0; jj < PL; jj++){ int q = pos - jj; if (q >= 0) s += prS[jj]*alS[q]; }
      pS[pos] = logf(fmaxf(s, 1e-6f));
      #pragma unroll
      for (int c = 0; c < SF; c++){
        float s2 = 0.f;
        #pragma unroll
        for (int k = 0; k < SK; k++){ int q = pos + k - 10; if (q>=0 && q<TENC) s2 += wFS[c*SK+k]*alS[q]; }
        fS[c*TENC + pos] = s2;
      }
    }
    __syncthreads();
    // 5. q = tanh
    if (tid < AD) qS[tid] = tanhf(attWb[tid] + part[tid] + part[128+tid] + part[256+tid] + part[384+tid]);
    __syncthreads();
    // 6. G = attV @ q
    if (tid < DF*DK){
      float a = 0.f;
      for (int k = 0; k < AD; k++) a += qS[k]*attVT[k*(DF*DK) + tid];
      GS[tid] = a;
    }
    __syncthreads();
    // 7. e[pos] = v . tanh(U f + T g + Tb) + p   (4 threads / pos)
    if (tid < 4*TENC){
      const int pos = tid >> 2, qr = tid & 3;
      float g[DF];
      #pragma unroll
      for (int c=0;c<DF;c++){
        float s=0.f;
        #pragma unroll
        for (int k=0;k<DK;k++){
          int q2 = pos + k - 10;
          if (q2>=0 && q2<TENC) s += alS[q2]*GS[c*DK+k];
        }
        g[c]=s;
      }
      float pp = 0.f;
      for (int h = qr*32; h < qr*32+32; h++){
        float u = tbS[h];
        #pragma unroll
        for (int s2=0;s2<SF;s2++) u += uS[h*SF+s2]*fS[s2*TENC+pos];
        #pragma unroll
        for (int c=0;c<DF;c++) u += tS2[h*DF+c]*g[c];
        pp += vS[h]*tanh_fast(u);
      }
      pp += __shfl_xor(pp,1);
      pp += __shfl_xor(pp,2);
      if (qr==0) eS[pos] = pp + pS[pos];
    }
    __syncthreads();
    // 8. softmax over 200
    float ex;
    {
      float v = (tid<TENC)? eS[tid] : -3.0e38f;
      for (int o=1;o<64;o<<=1) v = fmaxf(v, __shfl_xor(v,o));
      if ((tid&63)==0) rb[tid>>6] = v;
      __syncthreads();
      if (tid==0){ float m=rb[0]; for(int w=1;w<16;w++) m=fmaxf(m,rb[w]); rb[16]=m; }
      __syncthreads();
      float m = rb[16];
      ex = (tid<TENC)? expf(eS[tid]-m) : 0.f;
      float sv = ex;
      for (int o=1;o<64;o<<=1) sv += __shfl_xor(sv,o);
      __syncthreads();
      if ((tid&63)==0) rb[tid>>6] = sv;
      __syncthreads();
      if (tid==0){ float s=0.f; for(int w=0;w<16;w++) s+=rb[w]; rb[16]=1.f/s; }
      __syncthreads();
      float inv = rb[16];
      if (tid<TENC){
        float a = ex*inv;
        alS[tid] = a;
        out[1024000 + b*TENC*STEPS + tid*STEPS + t] = a;
      }
    }
    __syncthreads();
    // 9. ctx = align @ memory[b]  (nontemporal: keep weights L2-resident)
    {
      int grp = tid >> 8, j = tid & 255;
      float a0=0.f,a1=0.f;
      const float* mb = memory + (unsigned)b*TENC*MEM + j;
      for (int p=grp*50; p<grp*50+50; p+=2){
        a0 += alS[p  ]*__builtin_nontemporal_load(&mb[(p  )*MEM]);
        a1 += alS[p+1]*__builtin_nontemporal_load(&mb[(p+1)*MEM]);
      }
      part[grp*256+j] = a0+a1;
    }
    __syncthreads();
    if (tid < 256) ctxS[tid] = part[tid]+part[256+tid]+part[512+tid]+part[768+tid];
    __syncthreads();
    // 10. LSTM2 gates: K = [h1 256 | ctx 256] + h2 256
    {
      float a0 = bias2, a1 = 0.f, a2 = 0.f, a3 = 0.f;
      #pragma unroll 4
      for (int kk = 0; kk < 32; kk++){
        uint4 wv = *(const uint4*)(P3 + (unsigned)kk*8192u + tid*8u);
        const float* xp = h1S + 8*kk;
        FMA8(wv, xp, a0, a1, a2, a3)
      }
      #pragma unroll 4
      for (int kk = 32; kk < 64; kk++){
        uint4 wv = *(const uint4*)(P3 + (unsigned)kk*8192u + tid*8u);
        const float* xp = ctxS + 8*kk - 256;
        FMA8(wv, xp, a0, a1, a2, a3)
      }
      #pragma unroll 4
      for (int kk = 0; kk < 32; kk++){
        uint4 wv = *(const uint4*)(P4 + (unsigned)kk*8192u + tid*8u);
        const float* xp = h2S + 8*kk;
        FMA8(wv, xp, a0, a1, a2, a3)
      }
      gat[tid] = (a0+a1)+(a2+a3);
    }
    __syncthreads();
    // 11. LSTM2 state update
    if (tid < 256){
      float gi=gat[tid], gf=gat[256+tid], gg=gat[512+tid], go=gat[768+tid];
      float c = sigm(gf)*c2S[tid] + sigm(gi)*tanhf(gg);
      c2S[tid] = c;
      h2S[tid] = sigm(go)*tanhf(c);
    }
    __syncthreads();
    // 12. acoustic projection: 4 threads / output col over K=512 [h2,ctx]
    if (tid < 640){
      const int col = tid >> 2, q = tid & 3;
      float a0 = 0.f, a1 = 0.f, a2 = 0.f, a3 = 0.f;
      #pragma unroll 4
      for (int kk = q*16; kk < q*16+16; kk++){
        uint4 wv = *(const uint4*)(P5 + (unsigned)kk*1280u + col*8u);
        const float* xp = (kk < 32) ? (h2S + 8*kk) : (ctxS + 8*kk - 256);
        FMA8(wv, xp, a0, a1, a2, a3)
      }
      float acc = (a0+a1)+(a2+a3);
      acc += __shfl_xor(acc,1);
      acc += __shfl_xor(acc,2);
      if (q==0){
        const int m = col >> 1, r = col & 1;
        out[(unsigned)b*NMELS*TMELS + m*TMELS + 2*t + r] = acc + acbv;
      }
    }
    __syncthreads();
  }
}

extern "C" void kernel_launch(void* const* d_in, const int* in_sizes, int n_in,
                              void* d_out, int out_size, void* d_ws, size_t ws_size,
                              hipStream_t stream) {
  (void)in_sizes; (void)n_in; (void)out_size; (void)ws_size;
  const float* mels   = (const float*)d_in[0];
  const float* memory = (const float*)d_in[1];
  const float* pre_W1 = (const float*)d_in[2];
  const float* pre_b1 = (const float*)d_in[3];
  const float* pre_W2 = (const float*)d_in[4];
  const float* pre_b2 = (const float*)d_in[5];
  const float* al_Wih = (const float*)d_in[6];
  const float* al_Whh = (const float*)d_in[7];
  const float* al_bih = (const float*)d_in[8];
  const float* al_bhh = (const float*)d_in[9];
  const float* att_W  = (const float*)d_in[10];
  const float* att_Wb = (const float*)d_in[11];
  const float* att_V  = (const float*)d_in[12];
  const float* att_F  = (const float*)d_in[13];
  const float* att_U  = (const float*)d_in[14];
  const float* att_T  = (const float*)d_in[15];
  const float* att_Tb = (const float*)d_in[16];
  const float* att_v  = (const float*)d_in[17];
  const float* prior  = (const float*)d_in[18];
  const float* dl_Wih = (const float*)d_in[19];
  const float* dl_Whh = (const float*)d_in[20];
  const float* dl_bih = (const float*)d_in[21];
  const float* dl_bhh = (const float*)d_in[22];
  const float* ac_W   = (const float*)d_in[23];
  const float* ac_b   = (const float*)d_in[24];
  float* ws  = (float*)d_ws;
  unsigned short* hw = (unsigned short*)d_ws;
  float* out = (float*)d_out;

  auto TR = [&](const float* src, unsigned off, int R, int C){
    int n = R*C;
    trk<<<dim3((n+255)/256), dim3(256), 0, stream>>>(src, ws + off, R, C);
  };
  auto PKH = [&](const float* src, unsigned off_us, int R, int C){
    int n = R*C;
    pk8h<<<dim3((n+255)/256), dim3(256), 0, stream>>>(src, hw + off_us, R, C);
  };
  PKH(al_Wih, HP1, 1024, 384);
  PKH(al_Whh, HP2, 1024, 256);
  PKH(dl_Wih, HP3, 1024, 512);
  PKH(dl_Whh, HP4, 1024, 256);
  PKH(ac_W,   HP5, 160, 512);
  TR(att_W,  WS_ATTWT, 128, 256);
  TR(att_V,  WS_ATTVT, 168, 128);
  TR(pre_W1, WS_PW1T,  256, 80);
  TR(pre_W2, WS_PW2T,  128, 256);

  prenetk<<<dim3(STEPS), dim3(256), 0, stream>>>(mels, pre_b1, pre_b2, ws);

  decoder<<<dim3(BB), dim3(BLK), 0, stream>>>(
      al_bih, al_bhh, dl_bih, dl_bhh, prior, att_F,
      att_Wb, att_U, att_T, att_Tb, att_v, memory,
      ac_b, ws, out);
}